// Round 6
// baseline (448.563 us; speedup 1.0000x reference)
//
#include <hip/hip_runtime.h>
#include <hip/hip_bf16.h>
#include <math.h>

#define NN 1536
#define TT 10
#define DD 64
#define NHEAD 4
#define HDIM 16
#define PP 1178880   // NN*(NN-1)/2 = 4605 * 256 exactly; = 18420 * 64

// ws layout (float offsets)
#define WS_NODE0 0
#define WS_G1    98304
#define WS_G2    196608
#define WS_PART  294912              // jsplit*1536*64 (overlaps GI..TXYT, used before them)
#define WS_GI    294912              // 1536*128
#define WS_GJT   491520              // 128*1536
#define WS_W2F   688128              // 16384 ushort = 8192 float slots
#define WS_TXYT  696320              // 20*1536

using bf16x8 = __attribute__((ext_vector_type(8))) short;
using f32x4  = __attribute__((ext_vector_type(4))) float;

static __device__ __forceinline__ unsigned short f2bf_rn(float f) {
    unsigned int u = __float_as_uint(f);
    unsigned int r = (u + 0x7FFFu + ((u >> 16) & 1u)) >> 16;
    return (unsigned short)r;
}
static __device__ __forceinline__ float bf2f(unsigned short h) {
    return __uint_as_float(((unsigned int)h) << 16);
}

static __device__ __forceinline__ float dot64(const float* __restrict__ a,
                                              const float* __restrict__ b) {
    float s = 0.f;
#pragma unroll
    for (int c = 0; c < 64; c += 4) {
        float4 av = *reinterpret_cast<const float4*>(a + c);
        float4 bv = *reinterpret_cast<const float4*>(b + c);
        s = fmaf(av.x, bv.x, s);
        s = fmaf(av.y, bv.y, s);
        s = fmaf(av.z, bv.z, s);
        s = fmaf(av.w, bv.w, s);
    }
    return s;
}

// ---------------- Transformer encoder layer, one block (128 thr) per node ----------------
__global__ __launch_bounds__(128) void k_transformer(
    const float* __restrict__ traj,
    const float* __restrict__ wqkv, const float* __restrict__ bqkv,
    const float* __restrict__ wo,   const float* __restrict__ bo,
    const float* __restrict__ g1,   const float* __restrict__ b1,
    const float* __restrict__ fw1,  const float* __restrict__ fb1,
    const float* __restrict__ fw2,  const float* __restrict__ fb2,
    const float* __restrict__ g2,   const float* __restrict__ b2,
    float* __restrict__ node_out)
{
    __shared__ __align__(16) float xs[TT][DD];
    __shared__ __align__(16) float qkvs[TT][3 * DD];
    __shared__ __align__(16) float cs[TT][DD];
    __shared__ __align__(16) float ys[TT][DD];
    __shared__ float mv[TT][2];

    const int n = blockIdx.x, tid = threadIdx.x;
    const float* xg = traj + (size_t)n * TT * DD;

    for (int idx = tid; idx < TT * DD; idx += 128)
        xs[idx / DD][idx % DD] = xg[idx];
    __syncthreads();

    for (int idx = tid; idx < TT * 3 * DD; idx += 128) {
        int t = idx / (3 * DD), o = idx % (3 * DD);
        qkvs[t][o] = bqkv[o] + dot64(&xs[t][0], wqkv + o * DD);
    }
    __syncthreads();

    if (tid < NHEAD * TT) {
        int h = tid / TT, t = tid % TT;
        float sc[TT];
        float mx = -1e30f;
#pragma unroll
        for (int s = 0; s < TT; ++s) {
            float a = 0.f;
#pragma unroll
            for (int d = 0; d < HDIM; ++d)
                a = fmaf(qkvs[t][h * HDIM + d], qkvs[s][DD + h * HDIM + d], a);
            a *= 0.25f;
            sc[s] = a;
            mx = fmaxf(mx, a);
        }
        float den = 0.f;
#pragma unroll
        for (int s = 0; s < TT; ++s) { sc[s] = expf(sc[s] - mx); den += sc[s]; }
        float inv = 1.f / den;
#pragma unroll
        for (int d = 0; d < HDIM; ++d) {
            float a = 0.f;
#pragma unroll
            for (int s = 0; s < TT; ++s)
                a = fmaf(sc[s], qkvs[s][2 * DD + h * HDIM + d], a);
            cs[t][h * HDIM + d] = a * inv;
        }
    }
    __syncthreads();

    for (int idx = tid; idx < TT * DD; idx += 128) {
        int t = idx / DD, o = idx % DD;
        ys[t][o] = xs[t][o] + bo[o] + dot64(&cs[t][0], wo + o * DD);
    }
    __syncthreads();

    // LN1 stats: 80 threads, grouped-8 + shuffle (two-pass)
    {
        const int t8 = tid >> 3, s8 = tid & 7;
        if (t8 < TT) {
            const float* yr = &ys[t8][s8 * 8];
            float s1 = 0.f;
#pragma unroll
            for (int c = 0; c < 8; c += 4) {
                float4 v = *reinterpret_cast<const float4*>(yr + c);
                s1 += (v.x + v.y) + (v.z + v.w);
            }
#pragma unroll
            for (int m = 1; m < 8; m <<= 1) s1 += __shfl_xor(s1, m);
            const float mean = s1 * (1.f / DD);
            float s2 = 0.f;
#pragma unroll
            for (int c = 0; c < 8; c += 4) {
                float4 v = *reinterpret_cast<const float4*>(yr + c);
                float d0 = v.x - mean, d1 = v.y - mean, d2 = v.z - mean, d3 = v.w - mean;
                s2 = fmaf(d0, d0, fmaf(d1, d1, fmaf(d2, d2, fmaf(d3, d3, s2))));
            }
#pragma unroll
            for (int m = 1; m < 8; m <<= 1) s2 += __shfl_xor(s2, m);
            if (s8 == 0) {
                mv[t8][0] = mean;
                mv[t8][1] = rsqrtf(s2 * (1.f / DD) + 1e-5f);
            }
        }
    }
    __syncthreads();
    for (int idx = tid; idx < TT * DD; idx += 128) {
        int t = idx / DD, o = idx % DD;
        xs[t][o] = (ys[t][o] - mv[t][0]) * mv[t][1] * g1[o] + b1[o];
    }
    __syncthreads();

    for (int idx = tid; idx < TT * DD; idx += 128) {
        int t = idx / DD, p = idx % DD;
        cs[t][p] = fmaxf(fb1[p] + dot64(&xs[t][0], fw1 + p * DD), 0.f);
    }
    __syncthreads();

    for (int idx = tid; idx < TT * DD; idx += 128) {
        int t = idx / DD, o = idx % DD;
        ys[t][o] = xs[t][o] + fb2[o] + dot64(&cs[t][0], fw2 + o * DD);
    }
    __syncthreads();

    // LN2 stats
    {
        const int t8 = tid >> 3, s8 = tid & 7;
        if (t8 < TT) {
            const float* yr = &ys[t8][s8 * 8];
            float s1 = 0.f;
#pragma unroll
            for (int c = 0; c < 8; c += 4) {
                float4 v = *reinterpret_cast<const float4*>(yr + c);
                s1 += (v.x + v.y) + (v.z + v.w);
            }
#pragma unroll
            for (int m = 1; m < 8; m <<= 1) s1 += __shfl_xor(s1, m);
            const float mean = s1 * (1.f / DD);
            float s2 = 0.f;
#pragma unroll
            for (int c = 0; c < 8; c += 4) {
                float4 v = *reinterpret_cast<const float4*>(yr + c);
                float d0 = v.x - mean, d1 = v.y - mean, d2 = v.z - mean, d3 = v.w - mean;
                s2 = fmaf(d0, d0, fmaf(d1, d1, fmaf(d2, d2, fmaf(d3, d3, s2))));
            }
#pragma unroll
            for (int m = 1; m < 8; m <<= 1) s2 += __shfl_xor(s2, m);
            if (s8 == 0) {
                mv[t8][0] = mean;
                mv[t8][1] = rsqrtf(s2 * (1.f / DD) + 1e-5f);
            }
        }
    }
    __syncthreads();

    if (tid < DD) {
        float acc = 0.f;
#pragma unroll
        for (int t = 0; t < TT; ++t)
            acc += (ys[t][tid] - mv[t][0]) * mv[t][1];
        node_out[n * DD + tid] = acc * g2[tid] * (1.f / TT) + b2[tid];
    }
}

// ---------------- GCN: partial A@X over j-chunk ----------------
__global__ __launch_bounds__(256) void k_gcn_part(
    const float* __restrict__ A, const float* __restrict__ X,
    float* __restrict__ part, int jchunk)
{
    const int tid = threadIdx.x;
    const int r = tid >> 5;
    const int cp = tid & 31;
    const int i = blockIdx.x * 8 + r;
    const int j0 = blockIdx.y * jchunk;

    const float* arow = A + (size_t)i * NN + j0;
    const float* xp = X + (size_t)j0 * 64 + 2 * cp;

    float a0 = 0.f, a1 = 0.f;
#pragma unroll 4
    for (int j = 0; j < jchunk; ++j) {
        float av = arow[j];
        float2 xv = *reinterpret_cast<const float2*>(xp + (size_t)j * 64);
        a0 = fmaf(av, xv.x, a0);
        a1 = fmaf(av, xv.y, a1);
    }
    float2* op = reinterpret_cast<float2*>(part + ((size_t)blockIdx.y * NN + i) * 64 + 2 * cp);
    *op = make_float2(a0, a1);
}

// ---------------- GCN: reduce partials, apply W^T + bias + relu ----------------
__global__ __launch_bounds__(256) void k_gcn_red(
    const float* __restrict__ part, const float* __restrict__ W,
    const float* __restrict__ b, float* __restrict__ Y, int jsplit)
{
    __shared__ __align__(16) float yrow[4][68];
    const int o = threadIdx.x & 63, r = threadIdx.x >> 6;
    const int i = blockIdx.x * 4 + r;

    float s = 0.f;
    for (int jc = 0; jc < jsplit; ++jc)
        s += part[((size_t)jc * NN + i) * 64 + o];
    yrow[r][o] = s;
    __syncthreads();

    float z = b[o] + dot64(&yrow[r][0], W + o * 64);
    Y[(size_t)i * 64 + o] = fmaxf(z, 0.f);
}

// ---------------- prep (merged): gi table, gjT, w2f, txyT ----------------
__global__ __launch_bounds__(256) void k_prep(
    const float* __restrict__ node, const float* __restrict__ e_w1,
    const float* __restrict__ e_b1, const float* __restrict__ e_w2,
    const float* __restrict__ traj,
    float* __restrict__ gi_t, float* __restrict__ gjT,
    unsigned short* __restrict__ w2f, float* __restrict__ txyT)
{
    const int b = blockIdx.x;
    const int tid = threadIdx.x;
    if (b < NN / 2) {
        // two nodes per block
        __shared__ __align__(16) float ns[2][64];
        const int half = tid >> 7, o = tid & 127;
        if ((tid & 127) < 64) ns[half][tid & 63] = node[(size_t)(b * 2 + half) * 64 + (tid & 63)];
        __syncthreads();
        gi_t[(size_t)(b * 2 + half) * 128 + o] = e_b1[o] + dot64(ns[half], e_w1 + o * 138);
    } else if (b < NN / 2 + 128) {
        const int o = b - NN / 2;
        const float* w = e_w1 + o * 138 + 64;
        for (int j = tid; j < NN; j += 256)
            gjT[(size_t)o * NN + j] = dot64(node + (size_t)j * 64, w);
    } else if (b == NN / 2 + 128) {
        // w2f[((nt*4+kk)*2+half)*512 + lane*8 + e] = bf16 half of W2[k][n]
        for (int idx = tid; idx < 16384; idx += 256) {
            int e = idx & 7, lane = (idx >> 3) & 63;
            int half = (idx >> 9) & 1, kk = (idx >> 10) & 3, nt = (idx >> 12) & 3;
            int n = nt * 16 + (lane & 15);
            int k = kk * 32 + (lane >> 4) * 8 + e;
            float v = e_w2[n * 128 + k];
            unsigned short hi = f2bf_rn(v);
            unsigned short lo = f2bf_rn(v - bf2f(hi));
            w2f[idx] = half ? lo : hi;
        }
    } else {
        const int tc = b - (NN / 2 + 129);   // 0..19
        const int t = tc >> 1, c = tc & 1;
        for (int j = tid; j < NN; j += 256)
            txyT[(size_t)tc * NN + j] = traj[((size_t)j * TT + t) * DD + c];
    }
}

// ---------------- edge predictor: MFMA, 64 pairs/block, 4 waves ----------------
// L1 in fp32 -> truncation hi/lo split (a>=0) -> 3-term MFMA
__global__ __launch_bounds__(256, 4) void k_edge(
    const float* __restrict__ txyT,
    const float* __restrict__ gi_t, const float* __restrict__ gjT,
    const float* __restrict__ e_w1,
    const unsigned short* __restrict__ w2f, const float* __restrict__ e_b2,
    const float* __restrict__ e_w3, const float* __restrict__ e_b3,
    float* __restrict__ out)
{
    __shared__ __align__(16) unsigned short Ah[64 * 128];
    __shared__ __align__(16) unsigned short Al[64 * 128];
    __shared__ float zsh[4][64];

    const int tid  = threadIdx.x;
    const int lane = tid & 63;
    const int wv   = __builtin_amdgcn_readfirstlane(tid >> 6);  // wave 0..3
    const int p    = blockIdx.x * 64 + lane;

    // invert p -> (i, j)
    const float Df = (float)((2 * NN - 1) * (2 * NN - 1) - 8 * p);
    int i = (int)(((float)(2 * NN - 1) - sqrtf(Df)) * 0.5f);
    i = i < 0 ? 0 : (i > NN - 2 ? NN - 2 : i);
    while (i * (2 * NN - 1 - i) / 2 > p) --i;
    while ((i + 1) * (2 * NN - 2 - i) / 2 <= p) ++i;
    const int j = i + 1 + (p - i * (2 * NN - 1 - i) / 2);

    // ---- hist + dmin: ALL waves compute (keeps hist in regs, no barrier);
    //      wave 0 stores ----
    float hist[10];
    float dmin = 3.4e38f;
#pragma unroll
    for (int t = 0; t < 10; ++t) {
        float dx = txyT[(size_t)(2 * t) * NN + i] - txyT[(size_t)(2 * t) * NN + j];
        float dy = txyT[(size_t)(2 * t + 1) * NN + i] - txyT[(size_t)(2 * t + 1) * NN + j];
        float d = sqrtf(fmaf(dx, dx, dy * dy));
        dmin = fminf(dmin, d);
        hist[t] = 1.f / (1.f + expf(50.f - 10.f * d));
    }
    if (wv == 0) {
        out[PP + (size_t)p] = dmin;
        float* hp = out + 2 * (size_t)PP + (size_t)p * 10;
#pragma unroll
        for (int t = 0; t < 10; ++t) hp[t] = hist[t];
    }

    // ---- phase 1: L1 activations for o-window [32*wv, 32*wv+32) ----
    {
        const float* giRow = gi_t + (size_t)i * 128 + wv * 32;
        float4 giv[8];
#pragma unroll
        for (int q = 0; q < 8; ++q)
            giv[q] = *reinterpret_cast<const float4*>(giRow + q * 4);
        const float* gif = &giv[0].x;

        unsigned int ahp[16], alp[16];
#pragma unroll
        for (int q = 0; q < 16; ++q) {
            const int o = (wv << 5) + 2 * q;
            float a0 = gif[2 * q]     + gjT[(size_t)o * NN + j];
            float a1 = gif[2 * q + 1] + gjT[(size_t)(o + 1) * NN + j];
            const float* wh0 = e_w1 + o * 138 + 128;        // scalar path
            const float* wh1 = wh0 + 138;
#pragma unroll
            for (int t = 0; t < 10; ++t) {
                a0 = fmaf(hist[t], wh0[t], a0);
                a1 = fmaf(hist[t], wh1[t], a1);
            }
            a0 = fmaxf(a0, 0.f);
            a1 = fmaxf(a1, 0.f);
            // truncation split (a >= 0): hi = trunc16(a), lo = a - hi (exact), lo trunc'd
            const unsigned int u0 = __float_as_uint(a0), u1 = __float_as_uint(a1);
            ahp[q] = __builtin_amdgcn_perm(u1, u0, 0x07060302);
            const float l0 = a0 - __uint_as_float(u0 & 0xFFFF0000u);
            const float l1 = a1 - __uint_as_float(u1 & 0xFFFF0000u);
            alp[q] = __builtin_amdgcn_perm(__float_as_uint(l1), __float_as_uint(l0), 0x07060302);
        }

        char* ahb = (char*)Ah + lane * 256;
        char* alb = (char*)Al + lane * 256;
#pragma unroll
        for (int c = 0; c < 4; ++c) {
            const int boff = ((wv << 6) + (c << 4)) ^ ((lane & 7) << 4);
            *reinterpret_cast<uint4*>(ahb + boff) = *reinterpret_cast<uint4*>(&ahp[4 * c]);
            *reinterpret_cast<uint4*>(alb + boff) = *reinterpret_cast<uint4*>(&alp[4 * c]);
        }
    }

    // ---- B-frags for m-tile nt = wv ----
    bf16x8 bh[4], bl[4];
#pragma unroll
    for (int kk = 0; kk < 4; ++kk) {
        const unsigned short* bb = w2f + ((size_t)(wv * 4 + kk) * 2) * 512 + lane * 8;
        bh[kk] = *reinterpret_cast<const bf16x8*>(bb);
        bl[kk] = *reinterpret_cast<const bf16x8*>(bb + 512);
    }
    __syncthreads();

    // ---- phase 2: MFMA, K = 128, 3-term ----
    f32x4 acc[4];
#pragma unroll
    for (int pt = 0; pt < 4; ++pt) acc[pt] = (f32x4){0.f, 0.f, 0.f, 0.f};

    const char* ahr = (const char*)Ah;
    const char* alr = (const char*)Al;
#pragma unroll
    for (int kk = 0; kk < 4; ++kk) {
        const int boff = ((kk << 6) + ((lane >> 4) << 4)) ^ ((lane & 7) << 4);
#pragma unroll
        for (int pt = 0; pt < 4; ++pt) {
            const int row = pt * 16 + (lane & 15);
            bf16x8 afh = *reinterpret_cast<const bf16x8*>(ahr + row * 256 + boff);
            bf16x8 afl = *reinterpret_cast<const bf16x8*>(alr + row * 256 + boff);
            acc[pt] = __builtin_amdgcn_mfma_f32_16x16x32_bf16(afh, bh[kk], acc[pt], 0, 0, 0);
            acc[pt] = __builtin_amdgcn_mfma_f32_16x16x32_bf16(afh, bl[kk], acc[pt], 0, 0, 0);
            acc[pt] = __builtin_amdgcn_mfma_f32_16x16x32_bf16(afl, bh[kk], acc[pt], 0, 0, 0);
        }
    }

    // ---- epilogue ----
    {
        const int m = wv * 16 + (lane & 15);
        const float w3v = e_w3[m];
        const float b2v = e_b2[m];
#pragma unroll
        for (int pt = 0; pt < 4; ++pt) {
            float zs0 = fmaxf(acc[pt][0] + b2v, 0.f) * w3v;
            float zs1 = fmaxf(acc[pt][1] + b2v, 0.f) * w3v;
            float zs2 = fmaxf(acc[pt][2] + b2v, 0.f) * w3v;
            float zs3 = fmaxf(acc[pt][3] + b2v, 0.f) * w3v;
#pragma unroll
            for (int msk = 1; msk < 16; msk <<= 1) {
                zs0 += __shfl_xor(zs0, msk);
                zs1 += __shfl_xor(zs1, msk);
                zs2 += __shfl_xor(zs2, msk);
                zs3 += __shfl_xor(zs3, msk);
            }
            if ((lane & 15) == 0) {
                const int pr = pt * 16 + (lane >> 4) * 4;
                zsh[wv][pr]     = zs0;
                zsh[wv][pr + 1] = zs1;
                zsh[wv][pr + 2] = zs2;
                zsh[wv][pr + 3] = zs3;
            }
        }
    }
    __syncthreads();

    if (wv == 0) {
        float z = zsh[0][lane] + zsh[1][lane] + zsh[2][lane] + zsh[3][lane] + e_b3[0];
        out[p] = 1.f / (1.f + expf(-z));
    }
}

extern "C" void kernel_launch(void* const* d_in, const int* in_sizes, int n_in,
                              void* d_out, int out_size, void* d_ws, size_t ws_size,
                              hipStream_t stream) {
    const float* traj   = (const float*)d_in[0];
    const float* adj    = (const float*)d_in[1];
    const float* w_in   = (const float*)d_in[2];
    const float* b_in   = (const float*)d_in[3];
    const float* w_out  = (const float*)d_in[4];
    const float* b_out  = (const float*)d_in[5];
    const float* ln1g   = (const float*)d_in[6];
    const float* ln1b   = (const float*)d_in[7];
    const float* fw1    = (const float*)d_in[8];
    const float* fb1    = (const float*)d_in[9];
    const float* fw2    = (const float*)d_in[10];
    const float* fb2    = (const float*)d_in[11];
    const float* ln2g   = (const float*)d_in[12];
    const float* ln2b   = (const float*)d_in[13];
    const float* gcn_w  = (const float*)d_in[14];
    const float* gcn_b  = (const float*)d_in[15];
    const float* e_w1   = (const float*)d_in[16];
    const float* e_b1   = (const float*)d_in[17];
    const float* e_w2   = (const float*)d_in[18];
    const float* e_b2   = (const float*)d_in[19];
    const float* e_w3   = (const float*)d_in[20];
    const float* e_b3   = (const float*)d_in[21];

    float* ws    = (float*)d_ws;
    float* node0 = ws + WS_NODE0;
    float* g1b   = ws + WS_G1;
    float* g2b   = ws + WS_G2;
    float* partb = ws + WS_PART;
    float* gi    = ws + WS_GI;
    float* gjT   = ws + WS_GJT;
    unsigned short* w2f = (unsigned short*)(ws + WS_W2F);
    float* txyT  = ws + WS_TXYT;

    // jsplit=8 needs PART of 8*1536*64 floats (overlaps GI..TXYT, used earlier)
    const size_t need8 = (size_t)(WS_PART + 8 * NN * 64) * sizeof(float);
    const int jsplit = (ws_size >= need8) ? 8 : 4;
    const int jchunk = NN / jsplit;

    k_transformer<<<NN, 128, 0, stream>>>(traj, w_in, b_in, w_out, b_out,
                                          ln1g, ln1b, fw1, fb1, fw2, fb2,
                                          ln2g, ln2b, node0);

    dim3 pgrid(NN / 8, jsplit);
    k_gcn_part<<<pgrid, 256, 0, stream>>>(adj, node0, partb, jchunk);
    k_gcn_red<<<NN / 4, 256, 0, stream>>>(partb, gcn_w, gcn_b, g1b, jsplit);
    k_gcn_part<<<pgrid, 256, 0, stream>>>(adj, g1b, partb, jchunk);
    k_gcn_red<<<NN / 4, 256, 0, stream>>>(partb, gcn_w + 4096, gcn_b + 64, g2b, jsplit);
    k_gcn_part<<<pgrid, 256, 0, stream>>>(adj, g2b, partb, jchunk);
    k_gcn_red<<<NN / 4, 256, 0, stream>>>(partb, gcn_w + 8192, gcn_b + 128, g1b, jsplit);

    k_prep<<<NN / 2 + 149, 256, 0, stream>>>(g1b, e_w1, e_b1, e_w2, traj,
                                             gi, gjT, w2f, txyT);

    k_edge<<<PP / 64, 256, 0, stream>>>(txyT, gi, gjT, e_w1, w2f, e_b2,
                                        e_w3, e_b3, (float*)d_out);
}

// Round 8
// 421.435 us; speedup vs baseline: 1.0644x; 1.0644x over previous
//
#include <hip/hip_runtime.h>
#include <hip/hip_bf16.h>
#include <math.h>

#define NN 1536
#define TT 10
#define DD 64
#define NHEAD 4
#define HDIM 16
#define PP 1178880   // NN*(NN-1)/2 = 4605 * 256 exactly; = 18420 * 64

// ws layout (float offsets)
#define WS_NODE0 0
#define WS_G1    98304
#define WS_G2    196608
#define WS_PART  294912              // jsplit*1536*64 (overlaps GI..TXYT, used before them)
#define WS_GI    294912              // 1536*128
#define WS_GJT   491520              // 128*1536
#define WS_W2F   688128              // 16384 ushort = 8192 float slots
#define WS_TXYT  696320              // 20*1536

using bf16x8 = __attribute__((ext_vector_type(8))) short;
using f32x4  = __attribute__((ext_vector_type(4))) float;

// hardware-instruction transcendentals (v_sqrt_f32 / v_exp_f32 / v_rcp_f32),
// ~1 ulp rel error — fine vs 0.0469 absolute output threshold
static __device__ __forceinline__ float fsqrt(float x) {
    return __builtin_amdgcn_sqrtf(x);
}
static __device__ __forceinline__ float frcp(float x) {
    return __builtin_amdgcn_rcpf(x);
}
static __device__ __forceinline__ float fexp(float x) {
    return __builtin_amdgcn_exp2f(x * 1.44269504088896f);   // 2^(x*log2e)
}
static __device__ __forceinline__ float fsigmoid_neg(float e_arg) {
    // sigmoid with exp argument already negated: 1/(1+exp(e_arg))
    return frcp(1.f + fexp(e_arg));
}

static __device__ __forceinline__ unsigned short f2bf_rn(float f) {
    unsigned int u = __float_as_uint(f);
    unsigned int r = (u + 0x7FFFu + ((u >> 16) & 1u)) >> 16;
    return (unsigned short)r;
}
static __device__ __forceinline__ float bf2f(unsigned short h) {
    return __uint_as_float(((unsigned int)h) << 16);
}

static __device__ __forceinline__ float dot64(const float* __restrict__ a,
                                              const float* __restrict__ b) {
    float s = 0.f;
#pragma unroll
    for (int c = 0; c < 64; c += 4) {
        float4 av = *reinterpret_cast<const float4*>(a + c);
        float4 bv = *reinterpret_cast<const float4*>(b + c);
        s = fmaf(av.x, bv.x, s);
        s = fmaf(av.y, bv.y, s);
        s = fmaf(av.z, bv.z, s);
        s = fmaf(av.w, bv.w, s);
    }
    return s;
}

// ---------------- Transformer encoder layer, one block (128 thr) per node ----------------
__global__ __launch_bounds__(128) void k_transformer(
    const float* __restrict__ traj,
    const float* __restrict__ wqkv, const float* __restrict__ bqkv,
    const float* __restrict__ wo,   const float* __restrict__ bo,
    const float* __restrict__ g1,   const float* __restrict__ b1,
    const float* __restrict__ fw1,  const float* __restrict__ fb1,
    const float* __restrict__ fw2,  const float* __restrict__ fb2,
    const float* __restrict__ g2,   const float* __restrict__ b2,
    float* __restrict__ node_out)
{
    __shared__ __align__(16) float xs[TT][DD];
    __shared__ __align__(16) float qkvs[TT][3 * DD];
    __shared__ __align__(16) float cs[TT][DD];
    __shared__ __align__(16) float ys[TT][DD];
    __shared__ float mv[TT][2];

    const int n = blockIdx.x, tid = threadIdx.x;
    const float* xg = traj + (size_t)n * TT * DD;

    for (int idx = tid; idx < TT * DD; idx += 128)
        xs[idx / DD][idx % DD] = xg[idx];
    __syncthreads();

    for (int idx = tid; idx < TT * 3 * DD; idx += 128) {
        int t = idx / (3 * DD), o = idx % (3 * DD);
        qkvs[t][o] = bqkv[o] + dot64(&xs[t][0], wqkv + o * DD);
    }
    __syncthreads();

    if (tid < NHEAD * TT) {
        int h = tid / TT, t = tid % TT;
        float sc[TT];
        float mx = -1e30f;
#pragma unroll
        for (int s = 0; s < TT; ++s) {
            float a = 0.f;
#pragma unroll
            for (int d = 0; d < HDIM; ++d)
                a = fmaf(qkvs[t][h * HDIM + d], qkvs[s][DD + h * HDIM + d], a);
            a *= 0.25f;
            sc[s] = a;
            mx = fmaxf(mx, a);
        }
        float den = 0.f;
#pragma unroll
        for (int s = 0; s < TT; ++s) { sc[s] = fexp(sc[s] - mx); den += sc[s]; }
        float inv = frcp(den);
#pragma unroll
        for (int d = 0; d < HDIM; ++d) {
            float a = 0.f;
#pragma unroll
            for (int s = 0; s < TT; ++s)
                a = fmaf(sc[s], qkvs[s][2 * DD + h * HDIM + d], a);
            cs[t][h * HDIM + d] = a * inv;
        }
    }
    __syncthreads();

    for (int idx = tid; idx < TT * DD; idx += 128) {
        int t = idx / DD, o = idx % DD;
        ys[t][o] = xs[t][o] + bo[o] + dot64(&cs[t][0], wo + o * DD);
    }
    __syncthreads();

    // LN1 stats: 80 threads, grouped-8 + shuffle (two-pass)
    {
        const int t8 = tid >> 3, s8 = tid & 7;
        if (t8 < TT) {
            const float* yr = &ys[t8][s8 * 8];
            float s1 = 0.f;
#pragma unroll
            for (int c = 0; c < 8; c += 4) {
                float4 v = *reinterpret_cast<const float4*>(yr + c);
                s1 += (v.x + v.y) + (v.z + v.w);
            }
#pragma unroll
            for (int m = 1; m < 8; m <<= 1) s1 += __shfl_xor(s1, m);
            const float mean = s1 * (1.f / DD);
            float s2 = 0.f;
#pragma unroll
            for (int c = 0; c < 8; c += 4) {
                float4 v = *reinterpret_cast<const float4*>(yr + c);
                float d0 = v.x - mean, d1 = v.y - mean, d2 = v.z - mean, d3 = v.w - mean;
                s2 = fmaf(d0, d0, fmaf(d1, d1, fmaf(d2, d2, fmaf(d3, d3, s2))));
            }
#pragma unroll
            for (int m = 1; m < 8; m <<= 1) s2 += __shfl_xor(s2, m);
            if (s8 == 0) {
                mv[t8][0] = mean;
                mv[t8][1] = rsqrtf(s2 * (1.f / DD) + 1e-5f);
            }
        }
    }
    __syncthreads();
    for (int idx = tid; idx < TT * DD; idx += 128) {
        int t = idx / DD, o = idx % DD;
        xs[t][o] = (ys[t][o] - mv[t][0]) * mv[t][1] * g1[o] + b1[o];
    }
    __syncthreads();

    for (int idx = tid; idx < TT * DD; idx += 128) {
        int t = idx / DD, p = idx % DD;
        cs[t][p] = fmaxf(fb1[p] + dot64(&xs[t][0], fw1 + p * DD), 0.f);
    }
    __syncthreads();

    for (int idx = tid; idx < TT * DD; idx += 128) {
        int t = idx / DD, o = idx % DD;
        ys[t][o] = xs[t][o] + fb2[o] + dot64(&cs[t][0], fw2 + o * DD);
    }
    __syncthreads();

    // LN2 stats
    {
        const int t8 = tid >> 3, s8 = tid & 7;
        if (t8 < TT) {
            const float* yr = &ys[t8][s8 * 8];
            float s1 = 0.f;
#pragma unroll
            for (int c = 0; c < 8; c += 4) {
                float4 v = *reinterpret_cast<const float4*>(yr + c);
                s1 += (v.x + v.y) + (v.z + v.w);
            }
#pragma unroll
            for (int m = 1; m < 8; m <<= 1) s1 += __shfl_xor(s1, m);
            const float mean = s1 * (1.f / DD);
            float s2 = 0.f;
#pragma unroll
            for (int c = 0; c < 8; c += 4) {
                float4 v = *reinterpret_cast<const float4*>(yr + c);
                float d0 = v.x - mean, d1 = v.y - mean, d2 = v.z - mean, d3 = v.w - mean;
                s2 = fmaf(d0, d0, fmaf(d1, d1, fmaf(d2, d2, fmaf(d3, d3, s2))));
            }
#pragma unroll
            for (int m = 1; m < 8; m <<= 1) s2 += __shfl_xor(s2, m);
            if (s8 == 0) {
                mv[t8][0] = mean;
                mv[t8][1] = rsqrtf(s2 * (1.f / DD) + 1e-5f);
            }
        }
    }
    __syncthreads();

    if (tid < DD) {
        float acc = 0.f;
#pragma unroll
        for (int t = 0; t < TT; ++t)
            acc += (ys[t][tid] - mv[t][0]) * mv[t][1];
        node_out[n * DD + tid] = acc * g2[tid] * (1.f / TT) + b2[tid];
    }
}

// ---------------- GCN: partial A@X over j-chunk ----------------
__global__ __launch_bounds__(256) void k_gcn_part(
    const float* __restrict__ A, const float* __restrict__ X,
    float* __restrict__ part, int jchunk)
{
    const int tid = threadIdx.x;
    const int r = tid >> 5;
    const int cp = tid & 31;
    const int i = blockIdx.x * 8 + r;
    const int j0 = blockIdx.y * jchunk;

    const float* arow = A + (size_t)i * NN + j0;
    const float* xp = X + (size_t)j0 * 64 + 2 * cp;

    float a0 = 0.f, a1 = 0.f;
#pragma unroll 4
    for (int j = 0; j < jchunk; ++j) {
        float av = arow[j];
        float2 xv = *reinterpret_cast<const float2*>(xp + (size_t)j * 64);
        a0 = fmaf(av, xv.x, a0);
        a1 = fmaf(av, xv.y, a1);
    }
    float2* op = reinterpret_cast<float2*>(part + ((size_t)blockIdx.y * NN + i) * 64 + 2 * cp);
    *op = make_float2(a0, a1);
}

// ---------------- GCN: reduce partials, apply W^T + bias + relu ----------------
__global__ __launch_bounds__(256) void k_gcn_red(
    const float* __restrict__ part, const float* __restrict__ W,
    const float* __restrict__ b, float* __restrict__ Y, int jsplit)
{
    __shared__ __align__(16) float yrow[4][68];
    const int o = threadIdx.x & 63, r = threadIdx.x >> 6;
    const int i = blockIdx.x * 4 + r;

    float s = 0.f;
    for (int jc = 0; jc < jsplit; ++jc)
        s += part[((size_t)jc * NN + i) * 64 + o];
    yrow[r][o] = s;
    __syncthreads();

    float z = b[o] + dot64(&yrow[r][0], W + o * 64);
    Y[(size_t)i * 64 + o] = fmaxf(z, 0.f);
}

// ---------------- prep (merged): gi table, gjT, w2f, txyT ----------------
__global__ __launch_bounds__(256) void k_prep(
    const float* __restrict__ node, const float* __restrict__ e_w1,
    const float* __restrict__ e_b1, const float* __restrict__ e_w2,
    const float* __restrict__ traj,
    float* __restrict__ gi_t, float* __restrict__ gjT,
    unsigned short* __restrict__ w2f, float* __restrict__ txyT)
{
    const int b = blockIdx.x;
    const int tid = threadIdx.x;
    if (b < NN / 2) {
        __shared__ __align__(16) float ns[2][64];
        const int half = tid >> 7, o = tid & 127;
        if ((tid & 127) < 64) ns[half][tid & 63] = node[(size_t)(b * 2 + half) * 64 + (tid & 63)];
        __syncthreads();
        gi_t[(size_t)(b * 2 + half) * 128 + o] = e_b1[o] + dot64(ns[half], e_w1 + o * 138);
    } else if (b < NN / 2 + 128) {
        const int o = b - NN / 2;
        const float* w = e_w1 + o * 138 + 64;
        for (int j = tid; j < NN; j += 256)
            gjT[(size_t)o * NN + j] = dot64(node + (size_t)j * 64, w);
    } else if (b == NN / 2 + 128) {
        for (int idx = tid; idx < 16384; idx += 256) {
            int e = idx & 7, lane = (idx >> 3) & 63;
            int half = (idx >> 9) & 1, kk = (idx >> 10) & 3, nt = (idx >> 12) & 3;
            int n = nt * 16 + (lane & 15);
            int k = kk * 32 + (lane >> 4) * 8 + e;
            float v = e_w2[n * 128 + k];
            unsigned short hi = f2bf_rn(v);
            unsigned short lo = f2bf_rn(v - bf2f(hi));
            w2f[idx] = half ? lo : hi;
        }
    } else {
        const int tc = b - (NN / 2 + 129);   // 0..19
        const int t = tc >> 1, c = tc & 1;
        for (int j = tid; j < NN; j += 256)
            txyT[(size_t)tc * NN + j] = traj[((size_t)j * TT + t) * DD + c];
    }
}

// ---------------- edge predictor: MFMA, 64 pairs/block, 4 waves ----------------
__global__ __launch_bounds__(256, 4) void k_edge(
    const float* __restrict__ txyT,
    const float* __restrict__ gi_t, const float* __restrict__ gjT,
    const float* __restrict__ e_w1,
    const unsigned short* __restrict__ w2f, const float* __restrict__ e_b2,
    const float* __restrict__ e_w3, const float* __restrict__ e_b3,
    float* __restrict__ out)
{
    __shared__ __align__(16) unsigned short Ah[64 * 128];
    __shared__ __align__(16) unsigned short Al[64 * 128];
    __shared__ float zsh[4][64];

    const int tid  = threadIdx.x;
    const int lane = tid & 63;
    const int wv   = __builtin_amdgcn_readfirstlane(tid >> 6);  // wave 0..3
    const int p    = blockIdx.x * 64 + lane;

    // invert p -> (i, j)
    const float Df = (float)((2 * NN - 1) * (2 * NN - 1) - 8 * p);
    int i = (int)(((float)(2 * NN - 1) - fsqrt(Df)) * 0.5f);
    i = i < 0 ? 0 : (i > NN - 2 ? NN - 2 : i);
    while (i * (2 * NN - 1 - i) / 2 > p) --i;
    while ((i + 1) * (2 * NN - 2 - i) / 2 <= p) ++i;
    const int j = i + 1 + (p - i * (2 * NN - 1 - i) / 2);

    // ---- hist + dmin: all waves compute (regs, no barrier); wave 0 stores ----
    float hist[10];
    float dmin = 3.4e38f;
#pragma unroll
    for (int t = 0; t < 10; ++t) {
        float dx = txyT[(size_t)(2 * t) * NN + i] - txyT[(size_t)(2 * t) * NN + j];
        float dy = txyT[(size_t)(2 * t + 1) * NN + i] - txyT[(size_t)(2 * t + 1) * NN + j];
        float d = fsqrt(fmaf(dx, dx, dy * dy));
        dmin = fminf(dmin, d);
        hist[t] = fsigmoid_neg(50.f - 10.f * d);   // sigmoid(10d-50)
    }
    if (wv == 0) {
        out[PP + (size_t)p] = dmin;
        float* hp = out + 2 * (size_t)PP + (size_t)p * 10;
#pragma unroll
        for (int t = 0; t < 10; ++t) hp[t] = hist[t];
    }

    // ---- phase 1: L1 activations for o-window [32*wv, 32*wv+32) ----
    {
        const float* giRow = gi_t + (size_t)i * 128 + wv * 32;
        float4 giv[8];
#pragma unroll
        for (int q = 0; q < 8; ++q)
            giv[q] = *reinterpret_cast<const float4*>(giRow + q * 4);
        const float* gif = &giv[0].x;

        unsigned int ahp[16], alp[16];
#pragma unroll
        for (int q = 0; q < 16; ++q) {
            const int o = (wv << 5) + 2 * q;
            float a0 = gif[2 * q]     + gjT[(size_t)o * NN + j];
            float a1 = gif[2 * q + 1] + gjT[(size_t)(o + 1) * NN + j];
            const float* wh0 = e_w1 + o * 138 + 128;        // scalar path
            const float* wh1 = wh0 + 138;
#pragma unroll
            for (int t = 0; t < 10; ++t) {
                a0 = fmaf(hist[t], wh0[t], a0);
                a1 = fmaf(hist[t], wh1[t], a1);
            }
            a0 = fmaxf(a0, 0.f);
            a1 = fmaxf(a1, 0.f);
            const unsigned int u0 = __float_as_uint(a0), u1 = __float_as_uint(a1);
            ahp[q] = __builtin_amdgcn_perm(u1, u0, 0x07060302);
            const float l0 = a0 - __uint_as_float(u0 & 0xFFFF0000u);
            const float l1 = a1 - __uint_as_float(u1 & 0xFFFF0000u);
            alp[q] = __builtin_amdgcn_perm(__float_as_uint(l1), __float_as_uint(l0), 0x07060302);
        }

        char* ahb = (char*)Ah + lane * 256;
        char* alb = (char*)Al + lane * 256;
#pragma unroll
        for (int c = 0; c < 4; ++c) {
            const int boff = ((wv << 6) + (c << 4)) ^ ((lane & 7) << 4);
            *reinterpret_cast<uint4*>(ahb + boff) = *reinterpret_cast<uint4*>(&ahp[4 * c]);
            *reinterpret_cast<uint4*>(alb + boff) = *reinterpret_cast<uint4*>(&alp[4 * c]);
        }
    }

    // ---- B-frags for m-tile nt = wv ----
    bf16x8 bh[4], bl[4];
#pragma unroll
    for (int kk = 0; kk < 4; ++kk) {
        const unsigned short* bb = w2f + ((size_t)(wv * 4 + kk) * 2) * 512 + lane * 8;
        bh[kk] = *reinterpret_cast<const bf16x8*>(bb);
        bl[kk] = *reinterpret_cast<const bf16x8*>(bb + 512);
    }
    __syncthreads();

    // ---- phase 2: MFMA, K = 128, 3-term ----
    f32x4 acc[4];
#pragma unroll
    for (int pt = 0; pt < 4; ++pt) acc[pt] = (f32x4){0.f, 0.f, 0.f, 0.f};

    const char* ahr = (const char*)Ah;
    const char* alr = (const char*)Al;
#pragma unroll
    for (int kk = 0; kk < 4; ++kk) {
        const int boff = ((kk << 6) + ((lane >> 4) << 4)) ^ ((lane & 7) << 4);
#pragma unroll
        for (int pt = 0; pt < 4; ++pt) {
            const int row = pt * 16 + (lane & 15);
            bf16x8 afh = *reinterpret_cast<const bf16x8*>(ahr + row * 256 + boff);
            bf16x8 afl = *reinterpret_cast<const bf16x8*>(alr + row * 256 + boff);
            acc[pt] = __builtin_amdgcn_mfma_f32_16x16x32_bf16(afh, bh[kk], acc[pt], 0, 0, 0);
            acc[pt] = __builtin_amdgcn_mfma_f32_16x16x32_bf16(afh, bl[kk], acc[pt], 0, 0, 0);
            acc[pt] = __builtin_amdgcn_mfma_f32_16x16x32_bf16(afl, bh[kk], acc[pt], 0, 0, 0);
        }
    }

    // ---- epilogue ----
    {
        const int m = wv * 16 + (lane & 15);
        const float w3v = e_w3[m];
        const float b2v = e_b2[m];
#pragma unroll
        for (int pt = 0; pt < 4; ++pt) {
            float zs0 = fmaxf(acc[pt][0] + b2v, 0.f) * w3v;
            float zs1 = fmaxf(acc[pt][1] + b2v, 0.f) * w3v;
            float zs2 = fmaxf(acc[pt][2] + b2v, 0.f) * w3v;
            float zs3 = fmaxf(acc[pt][3] + b2v, 0.f) * w3v;
#pragma unroll
            for (int msk = 1; msk < 16; msk <<= 1) {
                zs0 += __shfl_xor(zs0, msk);
                zs1 += __shfl_xor(zs1, msk);
                zs2 += __shfl_xor(zs2, msk);
                zs3 += __shfl_xor(zs3, msk);
            }
            if ((lane & 15) == 0) {
                const int pr = pt * 16 + (lane >> 4) * 4;
                zsh[wv][pr]     = zs0;
                zsh[wv][pr + 1] = zs1;
                zsh[wv][pr + 2] = zs2;
                zsh[wv][pr + 3] = zs3;
            }
        }
    }
    __syncthreads();

    if (wv == 0) {
        float z = zsh[0][lane] + zsh[1][lane] + zsh[2][lane] + zsh[3][lane] + e_b3[0];
        out[p] = fsigmoid_neg(-z);
    }
}

extern "C" void kernel_launch(void* const* d_in, const int* in_sizes, int n_in,
                              void* d_out, int out_size, void* d_ws, size_t ws_size,
                              hipStream_t stream) {
    const float* traj   = (const float*)d_in[0];
    const float* adj    = (const float*)d_in[1];
    const float* w_in   = (const float*)d_in[2];
    const float* b_in   = (const float*)d_in[3];
    const float* w_out  = (const float*)d_in[4];
    const float* b_out  = (const float*)d_in[5];
    const float* ln1g   = (const float*)d_in[6];
    const float* ln1b   = (const float*)d_in[7];
    const float* fw1    = (const float*)d_in[8];
    const float* fb1    = (const float*)d_in[9];
    const float* fw2    = (const float*)d_in[10];
    const float* fb2    = (const float*)d_in[11];
    const float* ln2g   = (const float*)d_in[12];
    const float* ln2b   = (const float*)d_in[13];
    const float* gcn_w  = (const float*)d_in[14];
    const float* gcn_b  = (const float*)d_in[15];
    const float* e_w1   = (const float*)d_in[16];
    const float* e_b1   = (const float*)d_in[17];
    const float* e_w2   = (const float*)d_in[18];
    const float* e_b2   = (const float*)d_in[19];
    const float* e_w3   = (const float*)d_in[20];
    const float* e_b3   = (const float*)d_in[21];

    float* ws    = (float*)d_ws;
    float* node0 = ws + WS_NODE0;
    float* g1b   = ws + WS_G1;
    float* g2b   = ws + WS_G2;
    float* partb = ws + WS_PART;
    float* gi    = ws + WS_GI;
    float* gjT   = ws + WS_GJT;
    unsigned short* w2f = (unsigned short*)(ws + WS_W2F);
    float* txyT  = ws + WS_TXYT;

    const size_t need8 = (size_t)(WS_PART + 8 * NN * 64) * sizeof(float);
    const int jsplit = (ws_size >= need8) ? 8 : 4;
    const int jchunk = NN / jsplit;

    k_transformer<<<NN, 128, 0, stream>>>(traj, w_in, b_in, w_out, b_out,
                                          ln1g, ln1b, fw1, fb1, fw2, fb2,
                                          ln2g, ln2b, node0);

    dim3 pgrid(NN / 8, jsplit);
    k_gcn_part<<<pgrid, 256, 0, stream>>>(adj, node0, partb, jchunk);
    k_gcn_red<<<NN / 4, 256, 0, stream>>>(partb, gcn_w, gcn_b, g1b, jsplit);
    k_gcn_part<<<pgrid, 256, 0, stream>>>(adj, g1b, partb, jchunk);
    k_gcn_red<<<NN / 4, 256, 0, stream>>>(partb, gcn_w + 4096, gcn_b + 64, g2b, jsplit);
    k_gcn_part<<<pgrid, 256, 0, stream>>>(adj, g2b, partb, jchunk);
    k_gcn_red<<<NN / 4, 256, 0, stream>>>(partb, gcn_w + 8192, gcn_b + 128, g1b, jsplit);

    k_prep<<<NN / 2 + 149, 256, 0, stream>>>(g1b, e_w1, e_b1, e_w2, traj,
                                             gi, gjT, w2f, txyT);

    k_edge<<<PP / 64, 256, 0, stream>>>(txyT, gi, gjT, e_w1, w2f, e_b2,
                                        e_w3, e_b3, (float*)d_out);
}

// Round 9
// 410.449 us; speedup vs baseline: 1.0929x; 1.0268x over previous
//
#include <hip/hip_runtime.h>
#include <hip/hip_bf16.h>
#include <math.h>

#define NN 1536
#define TT 10
#define DD 64
#define NHEAD 4
#define HDIM 16
#define PP 1178880   // NN*(NN-1)/2 = 4605 * 256 exactly; = 18420 * 64

// ws layout (float offsets)
#define WS_NODE0 0
#define WS_G1    98304
#define WS_G2    196608
#define WS_PART  294912              // jsplit*1536*64 (overlaps GI..TXYT, used before them)
#define WS_GI    294912              // 1536*128
#define WS_GJT   491520              // 32*1536*4 (quad layout)
#define WS_W2F   688128              // 16384 ushort = 8192 float slots
#define WS_TXYT  696320              // 20*1536

using bf16x8 = __attribute__((ext_vector_type(8))) short;
using f32x4  = __attribute__((ext_vector_type(4))) float;

// hardware-instruction transcendentals (v_sqrt_f32 / v_exp_f32 / v_rcp_f32)
static __device__ __forceinline__ float fsqrt(float x) {
    return __builtin_amdgcn_sqrtf(x);
}
static __device__ __forceinline__ float frcp(float x) {
    return __builtin_amdgcn_rcpf(x);
}
static __device__ __forceinline__ float fexp(float x) {
    return __builtin_amdgcn_exp2f(x * 1.44269504088896f);   // 2^(x*log2e)
}
static __device__ __forceinline__ float fsigmoid_neg(float e_arg) {
    return frcp(1.f + fexp(e_arg));     // 1/(1+exp(e_arg))
}

static __device__ __forceinline__ unsigned short f2bf_rn(float f) {
    unsigned int u = __float_as_uint(f);
    unsigned int r = (u + 0x7FFFu + ((u >> 16) & 1u)) >> 16;
    return (unsigned short)r;
}
static __device__ __forceinline__ float bf2f(unsigned short h) {
    return __uint_as_float(((unsigned int)h) << 16);
}

static __device__ __forceinline__ float dot64(const float* __restrict__ a,
                                              const float* __restrict__ b) {
    float s = 0.f;
#pragma unroll
    for (int c = 0; c < 64; c += 4) {
        float4 av = *reinterpret_cast<const float4*>(a + c);
        float4 bv = *reinterpret_cast<const float4*>(b + c);
        s = fmaf(av.x, bv.x, s);
        s = fmaf(av.y, bv.y, s);
        s = fmaf(av.z, bv.z, s);
        s = fmaf(av.w, bv.w, s);
    }
    return s;
}

// ---------------- Transformer encoder layer, one block (128 thr) per node ----------------
__global__ __launch_bounds__(128) void k_transformer(
    const float* __restrict__ traj,
    const float* __restrict__ wqkv, const float* __restrict__ bqkv,
    const float* __restrict__ wo,   const float* __restrict__ bo,
    const float* __restrict__ g1,   const float* __restrict__ b1,
    const float* __restrict__ fw1,  const float* __restrict__ fb1,
    const float* __restrict__ fw2,  const float* __restrict__ fb2,
    const float* __restrict__ g2,   const float* __restrict__ b2,
    float* __restrict__ node_out)
{
    __shared__ __align__(16) float xs[TT][DD];
    __shared__ __align__(16) float qkvs[TT][3 * DD];
    __shared__ __align__(16) float cs[TT][DD];
    __shared__ __align__(16) float ys[TT][DD];
    __shared__ float mv[TT][2];

    const int n = blockIdx.x, tid = threadIdx.x;
    const float* xg = traj + (size_t)n * TT * DD;

    for (int idx = tid; idx < TT * DD; idx += 128)
        xs[idx / DD][idx % DD] = xg[idx];
    __syncthreads();

    for (int idx = tid; idx < TT * 3 * DD; idx += 128) {
        int t = idx / (3 * DD), o = idx % (3 * DD);
        qkvs[t][o] = bqkv[o] + dot64(&xs[t][0], wqkv + o * DD);
    }
    __syncthreads();

    if (tid < NHEAD * TT) {
        int h = tid / TT, t = tid % TT;
        float sc[TT];
        float mx = -1e30f;
#pragma unroll
        for (int s = 0; s < TT; ++s) {
            float a = 0.f;
#pragma unroll
            for (int d = 0; d < HDIM; ++d)
                a = fmaf(qkvs[t][h * HDIM + d], qkvs[s][DD + h * HDIM + d], a);
            a *= 0.25f;
            sc[s] = a;
            mx = fmaxf(mx, a);
        }
        float den = 0.f;
#pragma unroll
        for (int s = 0; s < TT; ++s) { sc[s] = fexp(sc[s] - mx); den += sc[s]; }
        float inv = frcp(den);
#pragma unroll
        for (int d = 0; d < HDIM; ++d) {
            float a = 0.f;
#pragma unroll
            for (int s = 0; s < TT; ++s)
                a = fmaf(sc[s], qkvs[s][2 * DD + h * HDIM + d], a);
            cs[t][h * HDIM + d] = a * inv;
        }
    }
    __syncthreads();

    for (int idx = tid; idx < TT * DD; idx += 128) {
        int t = idx / DD, o = idx % DD;
        ys[t][o] = xs[t][o] + bo[o] + dot64(&cs[t][0], wo + o * DD);
    }
    __syncthreads();

    // LN1 stats: 80 threads, grouped-8 + shuffle
    {
        const int t8 = tid >> 3, s8 = tid & 7;
        if (t8 < TT) {
            const float* yr = &ys[t8][s8 * 8];
            float s1 = 0.f;
#pragma unroll
            for (int c = 0; c < 8; c += 4) {
                float4 v = *reinterpret_cast<const float4*>(yr + c);
                s1 += (v.x + v.y) + (v.z + v.w);
            }
#pragma unroll
            for (int m = 1; m < 8; m <<= 1) s1 += __shfl_xor(s1, m);
            const float mean = s1 * (1.f / DD);
            float s2 = 0.f;
#pragma unroll
            for (int c = 0; c < 8; c += 4) {
                float4 v = *reinterpret_cast<const float4*>(yr + c);
                float d0 = v.x - mean, d1 = v.y - mean, d2 = v.z - mean, d3 = v.w - mean;
                s2 = fmaf(d0, d0, fmaf(d1, d1, fmaf(d2, d2, fmaf(d3, d3, s2))));
            }
#pragma unroll
            for (int m = 1; m < 8; m <<= 1) s2 += __shfl_xor(s2, m);
            if (s8 == 0) {
                mv[t8][0] = mean;
                mv[t8][1] = rsqrtf(s2 * (1.f / DD) + 1e-5f);
            }
        }
    }
    __syncthreads();
    for (int idx = tid; idx < TT * DD; idx += 128) {
        int t = idx / DD, o = idx % DD;
        xs[t][o] = (ys[t][o] - mv[t][0]) * mv[t][1] * g1[o] + b1[o];
    }
    __syncthreads();

    for (int idx = tid; idx < TT * DD; idx += 128) {
        int t = idx / DD, p = idx % DD;
        cs[t][p] = fmaxf(fb1[p] + dot64(&xs[t][0], fw1 + p * DD), 0.f);
    }
    __syncthreads();

    for (int idx = tid; idx < TT * DD; idx += 128) {
        int t = idx / DD, o = idx % DD;
        ys[t][o] = xs[t][o] + fb2[o] + dot64(&cs[t][0], fw2 + o * DD);
    }
    __syncthreads();

    // LN2 stats
    {
        const int t8 = tid >> 3, s8 = tid & 7;
        if (t8 < TT) {
            const float* yr = &ys[t8][s8 * 8];
            float s1 = 0.f;
#pragma unroll
            for (int c = 0; c < 8; c += 4) {
                float4 v = *reinterpret_cast<const float4*>(yr + c);
                s1 += (v.x + v.y) + (v.z + v.w);
            }
#pragma unroll
            for (int m = 1; m < 8; m <<= 1) s1 += __shfl_xor(s1, m);
            const float mean = s1 * (1.f / DD);
            float s2 = 0.f;
#pragma unroll
            for (int c = 0; c < 8; c += 4) {
                float4 v = *reinterpret_cast<const float4*>(yr + c);
                float d0 = v.x - mean, d1 = v.y - mean, d2 = v.z - mean, d3 = v.w - mean;
                s2 = fmaf(d0, d0, fmaf(d1, d1, fmaf(d2, d2, fmaf(d3, d3, s2))));
            }
#pragma unroll
            for (int m = 1; m < 8; m <<= 1) s2 += __shfl_xor(s2, m);
            if (s8 == 0) {
                mv[t8][0] = mean;
                mv[t8][1] = rsqrtf(s2 * (1.f / DD) + 1e-5f);
            }
        }
    }
    __syncthreads();

    if (tid < DD) {
        float acc = 0.f;
#pragma unroll
        for (int t = 0; t < TT; ++t)
            acc += (ys[t][tid] - mv[t][0]) * mv[t][1];
        node_out[n * DD + tid] = acc * g2[tid] * (1.f / TT) + b2[tid];
    }
}

// ---------------- GCN: partial A@X over j-chunk ----------------
__global__ __launch_bounds__(256) void k_gcn_part(
    const float* __restrict__ A, const float* __restrict__ X,
    float* __restrict__ part, int jchunk)
{
    const int tid = threadIdx.x;
    const int r = tid >> 5;
    const int cp = tid & 31;
    const int i = blockIdx.x * 8 + r;
    const int j0 = blockIdx.y * jchunk;

    const float* arow = A + (size_t)i * NN + j0;
    const float* xp = X + (size_t)j0 * 64 + 2 * cp;

    float a0 = 0.f, a1 = 0.f;
#pragma unroll 4
    for (int j = 0; j < jchunk; ++j) {
        float av = arow[j];
        float2 xv = *reinterpret_cast<const float2*>(xp + (size_t)j * 64);
        a0 = fmaf(av, xv.x, a0);
        a1 = fmaf(av, xv.y, a1);
    }
    float2* op = reinterpret_cast<float2*>(part + ((size_t)blockIdx.y * NN + i) * 64 + 2 * cp);
    *op = make_float2(a0, a1);
}

// ---------------- GCN: reduce partials, apply W^T + bias + relu ----------------
__global__ __launch_bounds__(256) void k_gcn_red(
    const float* __restrict__ part, const float* __restrict__ W,
    const float* __restrict__ b, float* __restrict__ Y, int jsplit)
{
    __shared__ __align__(16) float yrow[4][68];
    const int o = threadIdx.x & 63, r = threadIdx.x >> 6;
    const int i = blockIdx.x * 4 + r;

    float s = 0.f;
    for (int jc = 0; jc < jsplit; ++jc)
        s += part[((size_t)jc * NN + i) * 64 + o];
    yrow[r][o] = s;
    __syncthreads();

    float z = b[o] + dot64(&yrow[r][0], W + o * 64);
    Y[(size_t)i * 64 + o] = fmaxf(z, 0.f);
}

// ---------------- prep (merged): gi table, gjT4 (quad layout), w2f, txyT ----------------
__global__ __launch_bounds__(256) void k_prep(
    const float* __restrict__ node, const float* __restrict__ e_w1,
    const float* __restrict__ e_b1, const float* __restrict__ e_w2,
    const float* __restrict__ traj,
    float* __restrict__ gi_t, float* __restrict__ gjT4,
    unsigned short* __restrict__ w2f, float* __restrict__ txyT)
{
    const int b = blockIdx.x;
    const int tid = threadIdx.x;
    if (b < NN / 2) {
        // gi: two nodes per block
        __shared__ __align__(16) float ns[2][64];
        const int half = tid >> 7, o = tid & 127;
        if ((tid & 127) < 64) ns[half][tid & 63] = node[(size_t)(b * 2 + half) * 64 + (tid & 63)];
        __syncthreads();
        gi_t[(size_t)(b * 2 + half) * 128 + o] = e_b1[o] + dot64(ns[half], e_w1 + o * 138);
    } else if (b < NN / 2 + 192) {
        // gjT4[quad][j][k] = node[j] . w1b[4*quad+k]; 32 quads x 6 j-chunks
        const int s = b - NN / 2;
        const int quad = s & 31, jc = s >> 5;
        const int j = jc * 256 + tid;
        const float* nj = node + (size_t)j * 64;
        float4 r;
#pragma unroll
        for (int k = 0; k < 4; ++k)
            (&r.x)[k] = dot64(nj, e_w1 + (size_t)(4 * quad + k) * 138 + 64);
        *reinterpret_cast<float4*>(gjT4 + ((size_t)quad * NN + j) * 4) = r;
    } else if (b < NN / 2 + 192 + 64) {
        // w2f: 64 blocks x 256 threads = 16384 elems, one each
        const int idx = (b - (NN / 2 + 192)) * 256 + tid;
        int e = idx & 7, lane = (idx >> 3) & 63;
        int half = (idx >> 9) & 1, kk = (idx >> 10) & 3, nt = (idx >> 12) & 3;
        int n = nt * 16 + (lane & 15);
        int k = kk * 32 + (lane >> 4) * 8 + e;
        float v = e_w2[n * 128 + k];
        unsigned short hi = f2bf_rn(v);
        unsigned short lo = f2bf_rn(v - bf2f(hi));
        w2f[idx] = half ? lo : hi;
    } else {
        const int tc = b - (NN / 2 + 256);   // 0..19
        const int t = tc >> 1, c = tc & 1;
        for (int j = tid; j < NN; j += 256)
            txyT[(size_t)tc * NN + j] = traj[((size_t)j * TT + t) * DD + c];
    }
}

// ---------------- edge predictor: MFMA, 64 pairs/block, 4 waves ----------------
__global__ __launch_bounds__(256, 4) void k_edge(
    const float* __restrict__ txyT,
    const float* __restrict__ gi_t, const float* __restrict__ gjT4,
    const float* __restrict__ e_w1,
    const unsigned short* __restrict__ w2f, const float* __restrict__ e_b2,
    const float* __restrict__ e_w3, const float* __restrict__ e_b3,
    float* __restrict__ out)
{
    __shared__ __align__(16) unsigned short Ah[64 * 128];
    __shared__ __align__(16) unsigned short Al[64 * 128];
    __shared__ float hs[64][11];
    __shared__ float zsh[4][64];

    const int tid  = threadIdx.x;
    const int lane = tid & 63;
    const int wv   = __builtin_amdgcn_readfirstlane(tid >> 6);  // wave 0..3
    const int p    = blockIdx.x * 64 + lane;

    // invert p -> (i, j)
    const float Df = (float)((2 * NN - 1) * (2 * NN - 1) - 8 * p);
    int i = (int)(((float)(2 * NN - 1) - fsqrt(Df)) * 0.5f);
    i = i < 0 ? 0 : (i > NN - 2 ? NN - 2 : i);
    while (i * (2 * NN - 1 - i) / 2 > p) --i;
    while ((i + 1) * (2 * NN - 2 - i) / 2 <= p) ++i;
    const int j = i + 1 + (p - i * (2 * NN - 1 - i) / 2);

    // ---- hist + dmin: wave 0 only -> LDS; others wait ----
    if (wv == 0) {
        float dmin = 3.4e38f;
#pragma unroll
        for (int t = 0; t < 10; ++t) {
            float dx = txyT[(size_t)(2 * t) * NN + i] - txyT[(size_t)(2 * t) * NN + j];
            float dy = txyT[(size_t)(2 * t + 1) * NN + i] - txyT[(size_t)(2 * t + 1) * NN + j];
            float d = fsqrt(fmaf(dx, dx, dy * dy));
            dmin = fminf(dmin, d);
            float h = fsigmoid_neg(50.f - 10.f * d);   // sigmoid(10d-50)
            hs[lane][t] = h;
        }
        out[PP + (size_t)p] = dmin;
        float* hp = out + 2 * (size_t)PP + (size_t)p * 10;
#pragma unroll
        for (int t = 0; t < 10; ++t) hp[t] = hs[lane][t];
    }
    __syncthreads();

    float hist[10];
#pragma unroll
    for (int t = 0; t < 10; ++t) hist[t] = hs[lane][t];

    // ---- phase 1: L1 activations for o-window [32*wv, 32*wv+32) ----
    {
        const float* giRow = gi_t + (size_t)i * 128 + wv * 32;
        float4 giv[8];
#pragma unroll
        for (int q = 0; q < 8; ++q)
            giv[q] = *reinterpret_cast<const float4*>(giRow + q * 4);
        const float* gif = &giv[0].x;

        unsigned int ahp[16], alp[16];
#pragma unroll
        for (int q2 = 0; q2 < 8; ++q2) {
            const int o = (wv << 5) + 4 * q2;
            const float4 gj4 = *reinterpret_cast<const float4*>(
                gjT4 + ((size_t)(o >> 2) * NN + j) * 4);
            float av[4];
#pragma unroll
            for (int k = 0; k < 4; ++k) {
                float a = gif[4 * q2 + k] + (&gj4.x)[k];
                const float* wh = e_w1 + (o + k) * 138 + 128;   // uniform -> scalar
#pragma unroll
                for (int t = 0; t < 10; ++t) a = fmaf(hist[t], wh[t], a);
                av[k] = fmaxf(a, 0.f);
            }
            const unsigned int u0 = __float_as_uint(av[0]), u1 = __float_as_uint(av[1]);
            const unsigned int u2 = __float_as_uint(av[2]), u3 = __float_as_uint(av[3]);
            ahp[2 * q2]     = __builtin_amdgcn_perm(u1, u0, 0x07060302);
            ahp[2 * q2 + 1] = __builtin_amdgcn_perm(u3, u2, 0x07060302);
            const float l0 = av[0] - __uint_as_float(u0 & 0xFFFF0000u);
            const float l1 = av[1] - __uint_as_float(u1 & 0xFFFF0000u);
            const float l2 = av[2] - __uint_as_float(u2 & 0xFFFF0000u);
            const float l3 = av[3] - __uint_as_float(u3 & 0xFFFF0000u);
            alp[2 * q2]     = __builtin_amdgcn_perm(__float_as_uint(l1), __float_as_uint(l0), 0x07060302);
            alp[2 * q2 + 1] = __builtin_amdgcn_perm(__float_as_uint(l3), __float_as_uint(l2), 0x07060302);
        }

        char* ahb = (char*)Ah + lane * 256;
        char* alb = (char*)Al + lane * 256;
#pragma unroll
        for (int c = 0; c < 4; ++c) {
            const int boff = ((wv << 6) + (c << 4)) ^ ((lane & 7) << 4);
            *reinterpret_cast<uint4*>(ahb + boff) = *reinterpret_cast<uint4*>(&ahp[4 * c]);
            *reinterpret_cast<uint4*>(alb + boff) = *reinterpret_cast<uint4*>(&alp[4 * c]);
        }
    }

    // ---- B-frags for m-tile nt = wv ----
    bf16x8 bh[4], bl[4];
#pragma unroll
    for (int kk = 0; kk < 4; ++kk) {
        const unsigned short* bb = w2f + ((size_t)(wv * 4 + kk) * 2) * 512 + lane * 8;
        bh[kk] = *reinterpret_cast<const bf16x8*>(bb);
        bl[kk] = *reinterpret_cast<const bf16x8*>(bb + 512);
    }
    __syncthreads();

    // ---- phase 2: MFMA, K = 128, 3-term ----
    f32x4 acc[4];
#pragma unroll
    for (int pt = 0; pt < 4; ++pt) acc[pt] = (f32x4){0.f, 0.f, 0.f, 0.f};

    const char* ahr = (const char*)Ah;
    const char* alr = (const char*)Al;
#pragma unroll
    for (int kk = 0; kk < 4; ++kk) {
        const int boff = ((kk << 6) + ((lane >> 4) << 4)) ^ ((lane & 7) << 4);
#pragma unroll
        for (int pt = 0; pt < 4; ++pt) {
            const int row = pt * 16 + (lane & 15);
            bf16x8 afh = *reinterpret_cast<const bf16x8*>(ahr + row * 256 + boff);
            bf16x8 afl = *reinterpret_cast<const bf16x8*>(alr + row * 256 + boff);
            acc[pt] = __builtin_amdgcn_mfma_f32_16x16x32_bf16(afh, bh[kk], acc[pt], 0, 0, 0);
            acc[pt] = __builtin_amdgcn_mfma_f32_16x16x32_bf16(afh, bl[kk], acc[pt], 0, 0, 0);
            acc[pt] = __builtin_amdgcn_mfma_f32_16x16x32_bf16(afl, bh[kk], acc[pt], 0, 0, 0);
        }
    }

    // ---- epilogue ----
    {
        const int m = wv * 16 + (lane & 15);
        const float w3v = e_w3[m];
        const float b2v = e_b2[m];
#pragma unroll
        for (int pt = 0; pt < 4; ++pt) {
            float zs0 = fmaxf(acc[pt][0] + b2v, 0.f) * w3v;
            float zs1 = fmaxf(acc[pt][1] + b2v, 0.f) * w3v;
            float zs2 = fmaxf(acc[pt][2] + b2v, 0.f) * w3v;
            float zs3 = fmaxf(acc[pt][3] + b2v, 0.f) * w3v;
#pragma unroll
            for (int msk = 1; msk < 16; msk <<= 1) {
                zs0 += __shfl_xor(zs0, msk);
                zs1 += __shfl_xor(zs1, msk);
                zs2 += __shfl_xor(zs2, msk);
                zs3 += __shfl_xor(zs3, msk);
            }
            if ((lane & 15) == 0) {
                const int pr = pt * 16 + (lane >> 4) * 4;
                zsh[wv][pr]     = zs0;
                zsh[wv][pr + 1] = zs1;
                zsh[wv][pr + 2] = zs2;
                zsh[wv][pr + 3] = zs3;
            }
        }
    }
    __syncthreads();

    if (wv == 0) {
        float z = zsh[0][lane] + zsh[1][lane] + zsh[2][lane] + zsh[3][lane] + e_b3[0];
        out[p] = fsigmoid_neg(-z);
    }
}

extern "C" void kernel_launch(void* const* d_in, const int* in_sizes, int n_in,
                              void* d_out, int out_size, void* d_ws, size_t ws_size,
                              hipStream_t stream) {
    const float* traj   = (const float*)d_in[0];
    const float* adj    = (const float*)d_in[1];
    const float* w_in   = (const float*)d_in[2];
    const float* b_in   = (const float*)d_in[3];
    const float* w_out  = (const float*)d_in[4];
    const float* b_out  = (const float*)d_in[5];
    const float* ln1g   = (const float*)d_in[6];
    const float* ln1b   = (const float*)d_in[7];
    const float* fw1    = (const float*)d_in[8];
    const float* fb1    = (const float*)d_in[9];
    const float* fw2    = (const float*)d_in[10];
    const float* fb2    = (const float*)d_in[11];
    const float* ln2g   = (const float*)d_in[12];
    const float* ln2b   = (const float*)d_in[13];
    const float* gcn_w  = (const float*)d_in[14];
    const float* gcn_b  = (const float*)d_in[15];
    const float* e_w1   = (const float*)d_in[16];
    const float* e_b1   = (const float*)d_in[17];
    const float* e_w2   = (const float*)d_in[18];
    const float* e_b2   = (const float*)d_in[19];
    const float* e_w3   = (const float*)d_in[20];
    const float* e_b3   = (const float*)d_in[21];

    float* ws    = (float*)d_ws;
    float* node0 = ws + WS_NODE0;
    float* g1b   = ws + WS_G1;
    float* g2b   = ws + WS_G2;
    float* partb = ws + WS_PART;
    float* gi    = ws + WS_GI;
    float* gjT4  = ws + WS_GJT;
    unsigned short* w2f = (unsigned short*)(ws + WS_W2F);
    float* txyT  = ws + WS_TXYT;

    const size_t need8 = (size_t)(WS_PART + 8 * NN * 64) * sizeof(float);
    const int jsplit = (ws_size >= need8) ? 8 : 4;
    const int jchunk = NN / jsplit;

    k_transformer<<<NN, 128, 0, stream>>>(traj, w_in, b_in, w_out, b_out,
                                          ln1g, ln1b, fw1, fb1, fw2, fb2,
                                          ln2g, ln2b, node0);

    dim3 pgrid(NN / 8, jsplit);
    k_gcn_part<<<pgrid, 256, 0, stream>>>(adj, node0, partb, jchunk);
    k_gcn_red<<<NN / 4, 256, 0, stream>>>(partb, gcn_w, gcn_b, g1b, jsplit);
    k_gcn_part<<<pgrid, 256, 0, stream>>>(adj, g1b, partb, jchunk);
    k_gcn_red<<<NN / 4, 256, 0, stream>>>(partb, gcn_w + 4096, gcn_b + 64, g2b, jsplit);
    k_gcn_part<<<pgrid, 256, 0, stream>>>(adj, g2b, partb, jchunk);
    k_gcn_red<<<NN / 4, 256, 0, stream>>>(partb, gcn_w + 8192, gcn_b + 128, g1b, jsplit);

    k_prep<<<NN / 2 + 192 + 64 + 20, 256, 0, stream>>>(g1b, e_w1, e_b1, e_w2, traj,
                                                       gi, gjT4, w2f, txyT);

    k_edge<<<PP / 64, 256, 0, stream>>>(txyT, gi, gjT4, e_w1, w2f, e_b2,
                                        e_w3, e_b3, (float*)d_out);
}

// Round 10
// 323.382 us; speedup vs baseline: 1.3871x; 1.2692x over previous
//
#include <hip/hip_runtime.h>
#include <hip/hip_bf16.h>
#include <math.h>

#define NN 1536
#define TT 10
#define DD 64
#define NHEAD 4
#define HDIM 16
#define PP 1178880   // NN*(NN-1)/2 = 4605 * 256 exactly; = 18420 * 64
#define JSPLIT 4

// ws layout (float offsets) — total 727040 floats, lifetime-overlapped:
//   W2F    0       (8192)
//   TXYT   8192    (30720)  -> 38912
//   PART   38912   (NN*4*64 = 393216) -> 432128   [gi colocated: row i floats 0..128 after red3]
//   GJT4   432128  (196608) -> 628736             [g1b lives here during layers 1-2]
//   SLOTA  628736  (98304)  -> 727040             [node0, later g2b]
#define WS_W2F   0
#define WS_TXYT  8192
#define WS_PART  38912
#define WS_GJT4  432128
#define WS_SLOTA 628736

using bf16x8 = __attribute__((ext_vector_type(8))) short;
using f32x4  = __attribute__((ext_vector_type(4))) float;

static __device__ __forceinline__ float fsqrt(float x) { return __builtin_amdgcn_sqrtf(x); }
static __device__ __forceinline__ float frcp(float x)  { return __builtin_amdgcn_rcpf(x); }
static __device__ __forceinline__ float fexp(float x)  {
    return __builtin_amdgcn_exp2f(x * 1.44269504088896f);
}
static __device__ __forceinline__ float fsigmoid_neg(float e_arg) {
    return frcp(1.f + fexp(e_arg));     // 1/(1+exp(e_arg))
}

static __device__ __forceinline__ unsigned short f2bf_rn(float f) {
    unsigned int u = __float_as_uint(f);
    unsigned int r = (u + 0x7FFFu + ((u >> 16) & 1u)) >> 16;
    return (unsigned short)r;
}
static __device__ __forceinline__ float bf2f(unsigned short h) {
    return __uint_as_float(((unsigned int)h) << 16);
}

static __device__ __forceinline__ float dot64(const float* __restrict__ a,
                                              const float* __restrict__ b) {
    float s = 0.f;
#pragma unroll
    for (int c = 0; c < 64; c += 4) {
        float4 av = *reinterpret_cast<const float4*>(a + c);
        float4 bv = *reinterpret_cast<const float4*>(b + c);
        s = fmaf(av.x, bv.x, s);
        s = fmaf(av.y, bv.y, s);
        s = fmaf(av.z, bv.z, s);
        s = fmaf(av.w, bv.w, s);
    }
    return s;
}

// accumulate 16-wide chunk: acc += x[0..15] . w(4 float4 regs)
#define FMA16(acc, xr, w0, w1, w2, w3)                                   \
    {                                                                    \
        float4 x0 = *reinterpret_cast<const float4*>(xr);                \
        float4 x1 = *reinterpret_cast<const float4*>(xr + 4);            \
        float4 x2 = *reinterpret_cast<const float4*>(xr + 8);            \
        float4 x3 = *reinterpret_cast<const float4*>(xr + 12);           \
        acc = fmaf(x0.x, w0.x, acc); acc = fmaf(x0.y, w0.y, acc);        \
        acc = fmaf(x0.z, w0.z, acc); acc = fmaf(x0.w, w0.w, acc);        \
        acc = fmaf(x1.x, w1.x, acc); acc = fmaf(x1.y, w1.y, acc);        \
        acc = fmaf(x1.z, w1.z, acc); acc = fmaf(x1.w, w1.w, acc);        \
        acc = fmaf(x2.x, w2.x, acc); acc = fmaf(x2.y, w2.y, acc);        \
        acc = fmaf(x2.z, w2.z, acc); acc = fmaf(x2.w, w2.w, acc);        \
        acc = fmaf(x3.x, w3.x, acc); acc = fmaf(x3.y, w3.y, acc);        \
        acc = fmaf(x3.z, w3.z, acc); acc = fmaf(x3.w, w3.w, acc);        \
    }

// ---------------- Transformer encoder layer (+aux: w2f, txyT), 128 thr/block ----------------
__global__ __launch_bounds__(128) void k_transformer(
    const float* __restrict__ traj,
    const float* __restrict__ wqkv, const float* __restrict__ bqkv,
    const float* __restrict__ wo,   const float* __restrict__ bo,
    const float* __restrict__ g1,   const float* __restrict__ b1,
    const float* __restrict__ fw1,  const float* __restrict__ fb1,
    const float* __restrict__ fw2,  const float* __restrict__ fb2,
    const float* __restrict__ g2,   const float* __restrict__ b2,
    const float* __restrict__ e_w2,
    float* __restrict__ node_out, unsigned short* __restrict__ w2f,
    float* __restrict__ txyT)
{
    const int bid = blockIdx.x, tid = threadIdx.x;

    if (bid >= NN) {
        const int s = bid - NN;
        if (s < 64) {
            // w2f: MFMA B-frag hi/lo tables for W2
#pragma unroll
            for (int q = 0; q < 2; ++q) {
                const int idx = s * 256 + q * 128 + tid;
                int e = idx & 7, lane = (idx >> 3) & 63;
                int half = (idx >> 9) & 1, kk = (idx >> 10) & 3, nt = (idx >> 12) & 3;
                int n = nt * 16 + (lane & 15);
                int k = kk * 32 + (lane >> 4) * 8 + e;
                float v = e_w2[n * 128 + k];
                unsigned short hi = f2bf_rn(v);
                unsigned short lo = f2bf_rn(v - bf2f(hi));
                w2f[idx] = half ? lo : hi;
            }
        } else {
            const int tc = s - 64;       // 0..19
            const int t = tc >> 1, c = tc & 1;
            for (int j = tid; j < NN; j += 128)
                txyT[(size_t)tc * NN + j] = traj[((size_t)j * TT + t) * DD + c];
        }
        return;
    }

    __shared__ __align__(16) float xs[TT][DD];
    __shared__ __align__(16) float qkvs[TT][3 * DD];
    __shared__ __align__(16) float cs[TT][DD];
    __shared__ __align__(16) float ys[TT][DD];
    __shared__ float mv[TT][2];

    const float* xg = traj + (size_t)bid * TT * DD;
    for (int idx = tid; idx < TT * DD; idx += 128)
        xs[idx / DD][idx % DD] = xg[idx];
    __syncthreads();

    // ---- QKV: thread owns column o; weight row in regs, reused over t ----
    {
        // part A: o = tid (0..127), all 10 t's
        float acc[TT];
        const float bq = bqkv[tid];
#pragma unroll
        for (int t = 0; t < TT; ++t) acc[t] = bq;
        const float* wrow = wqkv + (size_t)tid * DD;
#pragma unroll
        for (int c = 0; c < 4; ++c) {
            float4 w0 = *reinterpret_cast<const float4*>(wrow + 16 * c);
            float4 w1 = *reinterpret_cast<const float4*>(wrow + 16 * c + 4);
            float4 w2 = *reinterpret_cast<const float4*>(wrow + 16 * c + 8);
            float4 w3 = *reinterpret_cast<const float4*>(wrow + 16 * c + 12);
#pragma unroll
            for (int t = 0; t < TT; ++t)
                FMA16(acc[t], &xs[t][16 * c], w0, w1, w2, w3);
        }
#pragma unroll
        for (int t = 0; t < TT; ++t) qkvs[t][tid] = acc[t];

        // part B: o = 128 + (tid>>1), t-half = tid&1 (5 t's)
        const int o2 = 128 + (tid >> 1);
        const int t0 = (tid & 1) * 5;
        float acc2[5];
        const float bq2 = bqkv[o2];
#pragma unroll
        for (int tt = 0; tt < 5; ++tt) acc2[tt] = bq2;
        const float* wrow2 = wqkv + (size_t)o2 * DD;
#pragma unroll
        for (int c = 0; c < 4; ++c) {
            float4 w0 = *reinterpret_cast<const float4*>(wrow2 + 16 * c);
            float4 w1 = *reinterpret_cast<const float4*>(wrow2 + 16 * c + 4);
            float4 w2 = *reinterpret_cast<const float4*>(wrow2 + 16 * c + 8);
            float4 w3 = *reinterpret_cast<const float4*>(wrow2 + 16 * c + 12);
#pragma unroll
            for (int tt = 0; tt < 5; ++tt)
                FMA16(acc2[tt], &xs[t0 + tt][16 * c], w0, w1, w2, w3);
        }
#pragma unroll
        for (int tt = 0; tt < 5; ++tt) qkvs[t0 + tt][o2] = acc2[tt];
    }
    __syncthreads();

    // ---- attention (40 threads) ----
    if (tid < NHEAD * TT) {
        int h = tid / TT, t = tid % TT;
        float sc[TT];
        float mx = -1e30f;
#pragma unroll
        for (int s = 0; s < TT; ++s) {
            float a = 0.f;
#pragma unroll
            for (int d = 0; d < HDIM; ++d)
                a = fmaf(qkvs[t][h * HDIM + d], qkvs[s][DD + h * HDIM + d], a);
            a *= 0.25f;
            sc[s] = a;
            mx = fmaxf(mx, a);
        }
        float den = 0.f;
#pragma unroll
        for (int s = 0; s < TT; ++s) { sc[s] = fexp(sc[s] - mx); den += sc[s]; }
        float inv = frcp(den);
#pragma unroll
        for (int d = 0; d < HDIM; ++d) {
            float a = 0.f;
#pragma unroll
            for (int s = 0; s < TT; ++s)
                a = fmaf(sc[s], qkvs[s][2 * DD + h * HDIM + d], a);
            cs[t][h * HDIM + d] = a * inv;
        }
    }
    __syncthreads();

    // ---- out-proj + residual: o = tid&63, t-half = tid>>6 ----
    {
        const int o = tid & 63, t0 = (tid >> 6) * 5;
        float acc[5];
        const float bv = bo[o];
#pragma unroll
        for (int tt = 0; tt < 5; ++tt) acc[tt] = bv;
        const float* wrow = wo + (size_t)o * DD;
#pragma unroll
        for (int c = 0; c < 4; ++c) {
            float4 w0 = *reinterpret_cast<const float4*>(wrow + 16 * c);
            float4 w1 = *reinterpret_cast<const float4*>(wrow + 16 * c + 4);
            float4 w2 = *reinterpret_cast<const float4*>(wrow + 16 * c + 8);
            float4 w3 = *reinterpret_cast<const float4*>(wrow + 16 * c + 12);
#pragma unroll
            for (int tt = 0; tt < 5; ++tt)
                FMA16(acc[tt], &cs[t0 + tt][16 * c], w0, w1, w2, w3);
        }
#pragma unroll
        for (int tt = 0; tt < 5; ++tt)
            ys[t0 + tt][o] = xs[t0 + tt][o] + acc[tt];
    }
    __syncthreads();

    // ---- LN1 stats ----
    {
        const int t8 = tid >> 3, s8 = tid & 7;
        if (t8 < TT) {
            const float* yr = &ys[t8][s8 * 8];
            float s1 = 0.f;
#pragma unroll
            for (int c = 0; c < 8; c += 4) {
                float4 v = *reinterpret_cast<const float4*>(yr + c);
                s1 += (v.x + v.y) + (v.z + v.w);
            }
#pragma unroll
            for (int m = 1; m < 8; m <<= 1) s1 += __shfl_xor(s1, m);
            const float mean = s1 * (1.f / DD);
            float s2 = 0.f;
#pragma unroll
            for (int c = 0; c < 8; c += 4) {
                float4 v = *reinterpret_cast<const float4*>(yr + c);
                float d0 = v.x - mean, d1 = v.y - mean, d2 = v.z - mean, d3 = v.w - mean;
                s2 = fmaf(d0, d0, fmaf(d1, d1, fmaf(d2, d2, fmaf(d3, d3, s2))));
            }
#pragma unroll
            for (int m = 1; m < 8; m <<= 1) s2 += __shfl_xor(s2, m);
            if (s8 == 0) {
                mv[t8][0] = mean;
                mv[t8][1] = rsqrtf(s2 * (1.f / DD) + 1e-5f);
            }
        }
    }
    __syncthreads();
    for (int idx = tid; idx < TT * DD; idx += 128) {
        int t = idx / DD, o = idx % DD;
        xs[t][o] = (ys[t][o] - mv[t][0]) * mv[t][1] * g1[o] + b1[o];
    }
    __syncthreads();

    // ---- FF1 (relu): p = tid&63 ----
    {
        const int pcol = tid & 63, t0 = (tid >> 6) * 5;
        float acc[5];
        const float bv = fb1[pcol];
#pragma unroll
        for (int tt = 0; tt < 5; ++tt) acc[tt] = bv;
        const float* wrow = fw1 + (size_t)pcol * DD;
#pragma unroll
        for (int c = 0; c < 4; ++c) {
            float4 w0 = *reinterpret_cast<const float4*>(wrow + 16 * c);
            float4 w1 = *reinterpret_cast<const float4*>(wrow + 16 * c + 4);
            float4 w2 = *reinterpret_cast<const float4*>(wrow + 16 * c + 8);
            float4 w3 = *reinterpret_cast<const float4*>(wrow + 16 * c + 12);
#pragma unroll
            for (int tt = 0; tt < 5; ++tt)
                FMA16(acc[tt], &xs[t0 + tt][16 * c], w0, w1, w2, w3);
        }
#pragma unroll
        for (int tt = 0; tt < 5; ++tt)
            cs[t0 + tt][pcol] = fmaxf(acc[tt], 0.f);
    }
    __syncthreads();

    // ---- FF2 + residual ----
    {
        const int o = tid & 63, t0 = (tid >> 6) * 5;
        float acc[5];
        const float bv = fb2[o];
#pragma unroll
        for (int tt = 0; tt < 5; ++tt) acc[tt] = bv;
        const float* wrow = fw2 + (size_t)o * DD;
#pragma unroll
        for (int c = 0; c < 4; ++c) {
            float4 w0 = *reinterpret_cast<const float4*>(wrow + 16 * c);
            float4 w1 = *reinterpret_cast<const float4*>(wrow + 16 * c + 4);
            float4 w2 = *reinterpret_cast<const float4*>(wrow + 16 * c + 8);
            float4 w3 = *reinterpret_cast<const float4*>(wrow + 16 * c + 12);
#pragma unroll
            for (int tt = 0; tt < 5; ++tt)
                FMA16(acc[tt], &cs[t0 + tt][16 * c], w0, w1, w2, w3);
        }
#pragma unroll
        for (int tt = 0; tt < 5; ++tt)
            ys[t0 + tt][o] = xs[t0 + tt][o] + acc[tt];
    }
    __syncthreads();

    // ---- LN2 stats ----
    {
        const int t8 = tid >> 3, s8 = tid & 7;
        if (t8 < TT) {
            const float* yr = &ys[t8][s8 * 8];
            float s1 = 0.f;
#pragma unroll
            for (int c = 0; c < 8; c += 4) {
                float4 v = *reinterpret_cast<const float4*>(yr + c);
                s1 += (v.x + v.y) + (v.z + v.w);
            }
#pragma unroll
            for (int m = 1; m < 8; m <<= 1) s1 += __shfl_xor(s1, m);
            const float mean = s1 * (1.f / DD);
            float s2 = 0.f;
#pragma unroll
            for (int c = 0; c < 8; c += 4) {
                float4 v = *reinterpret_cast<const float4*>(yr + c);
                float d0 = v.x - mean, d1 = v.y - mean, d2 = v.z - mean, d3 = v.w - mean;
                s2 = fmaf(d0, d0, fmaf(d1, d1, fmaf(d2, d2, fmaf(d3, d3, s2))));
            }
#pragma unroll
            for (int m = 1; m < 8; m <<= 1) s2 += __shfl_xor(s2, m);
            if (s8 == 0) {
                mv[t8][0] = mean;
                mv[t8][1] = rsqrtf(s2 * (1.f / DD) + 1e-5f);
            }
        }
    }
    __syncthreads();

    if (tid < DD) {
        float acc = 0.f;
#pragma unroll
        for (int t = 0; t < TT; ++t)
            acc += (ys[t][tid] - mv[t][0]) * mv[t][1];
        node_out[bid * DD + tid] = acc * g2[tid] * (1.f / TT) + b2[tid];
    }
}

// ---------------- GCN: partial A@X over j-chunk; part layout [i][jc][64] ----------------
__global__ __launch_bounds__(256) void k_gcn_part(
    const float* __restrict__ A, const float* __restrict__ X,
    float* __restrict__ part)
{
    const int tid = threadIdx.x;
    const int r = tid >> 5;
    const int cp = tid & 31;
    const int i = blockIdx.x * 8 + r;
    const int jc = blockIdx.y;
    const int j0 = jc * (NN / JSPLIT);

    const float* arow = A + (size_t)i * NN + j0;
    const float* xp = X + (size_t)j0 * 64 + 2 * cp;

    float a0 = 0.f, a1 = 0.f;
#pragma unroll 4
    for (int j = 0; j < NN / JSPLIT; ++j) {
        float av = arow[j];
        float2 xv = *reinterpret_cast<const float2*>(xp + (size_t)j * 64);
        a0 = fmaf(av, xv.x, a0);
        a1 = fmaf(av, xv.y, a1);
    }
    float2* op = reinterpret_cast<float2*>(part + ((size_t)i * JSPLIT + jc) * 64 + 2 * cp);
    *op = make_float2(a0, a1);
}

// ---------------- GCN red (layers 1,2): reduce partials, W^T + bias + relu ----------------
__global__ __launch_bounds__(256) void k_gcn_red(
    const float* __restrict__ part, const float* __restrict__ W,
    const float* __restrict__ b, float* __restrict__ Y)
{
    __shared__ __align__(16) float yrow[4][68];
    const int o = threadIdx.x & 63, r = threadIdx.x >> 6;
    const int i = blockIdx.x * 4 + r;

    float s = 0.f;
#pragma unroll
    for (int jc = 0; jc < JSPLIT; ++jc)
        s += part[((size_t)i * JSPLIT + jc) * 64 + o];
    yrow[r][o] = s;
    __syncthreads();

    float z = b[o] + dot64(&yrow[r][0], W + o * 64);
    Y[(size_t)i * 64 + o] = fmaxf(z, 0.f);
}

// ---------------- GCN red layer 3 + fused edge-prep (gi into part rows, gjT4) ----------------
__global__ __launch_bounds__(256) void k_gcn_red3(
    float* __restrict__ part, const float* __restrict__ W,
    const float* __restrict__ b,
    const float* __restrict__ e_w1, const float* __restrict__ e_b1,
    float* __restrict__ gjT4)
{
    __shared__ __align__(16) float nrow[4][68];
    const int tid = threadIdx.x;
    const int o = tid & 63, r = tid >> 6;
    const int i0 = blockIdx.x * 4;

    float s = 0.f;
#pragma unroll
    for (int jc = 0; jc < JSPLIT; ++jc)
        s += part[((size_t)(i0 + r) * JSPLIT + jc) * 64 + o];
    __shared__ __align__(16) float yrow[4][68];
    yrow[r][o] = s;
    __syncthreads();

    float z = b[o] + dot64(&yrow[r][0], W + o * 64);
    nrow[r][o] = fmaxf(z, 0.f);
    __syncthreads();

    // gi: 4 rows x 128 o -> 2 per thread; write into part's own rows (floats 0..128)
#pragma unroll
    for (int pass = 0; pass < 2; ++pass) {
        const int idx = pass * 256 + tid;
        const int rr = idx >> 7, oo = idx & 127;
        part[(size_t)(i0 + rr) * 256 + oo] =
            e_b1[oo] + dot64(&nrow[rr][0], e_w1 + oo * 138);
    }
    // gjT4[quad][j][k]
#pragma unroll
    for (int pass = 0; pass < 2; ++pass) {
        const int idx = pass * 256 + tid;
        const int rr = idx >> 7, oo = idx & 127;
        float v = dot64(&nrow[rr][0], e_w1 + oo * 138 + 64);
        gjT4[((size_t)(oo >> 2) * NN + (i0 + rr)) * 4 + (oo & 3)] = v;
    }
}

// ---------------- edge predictor: MFMA, 64 pairs/block, 4 waves ----------------
__global__ __launch_bounds__(256, 4) void k_edge(
    const float* __restrict__ txyT,
    const float* __restrict__ gi_t /* stride 256 */, const float* __restrict__ gjT4,
    const float* __restrict__ e_w1,
    const unsigned short* __restrict__ w2f, const float* __restrict__ e_b2,
    const float* __restrict__ e_w3, const float* __restrict__ e_b3,
    float* __restrict__ out)
{
    __shared__ __align__(16) unsigned short Ah[64 * 128];
    __shared__ __align__(16) unsigned short Al[64 * 128];
    __shared__ float hs[64][11];
    __shared__ float zsh[4][64];

    const int tid  = threadIdx.x;
    const int lane = tid & 63;
    const int wv   = __builtin_amdgcn_readfirstlane(tid >> 6);  // wave 0..3
    const int p    = blockIdx.x * 64 + lane;

    // invert p -> (i, j)
    const float Df = (float)((2 * NN - 1) * (2 * NN - 1) - 8 * p);
    int i = (int)(((float)(2 * NN - 1) - fsqrt(Df)) * 0.5f);
    i = i < 0 ? 0 : (i > NN - 2 ? NN - 2 : i);
    while (i * (2 * NN - 1 - i) / 2 > p) --i;
    while ((i + 1) * (2 * NN - 2 - i) / 2 <= p) ++i;
    const int j = i + 1 + (p - i * (2 * NN - 1 - i) / 2);

    // ---- hist + dmin: wave 0 only -> LDS ----
    if (wv == 0) {
        float dmin = 3.4e38f;
#pragma unroll
        for (int t = 0; t < 10; ++t) {
            float dx = txyT[(size_t)(2 * t) * NN + i] - txyT[(size_t)(2 * t) * NN + j];
            float dy = txyT[(size_t)(2 * t + 1) * NN + i] - txyT[(size_t)(2 * t + 1) * NN + j];
            float d = fsqrt(fmaf(dx, dx, dy * dy));
            dmin = fminf(dmin, d);
            float h = fsigmoid_neg(50.f - 10.f * d);   // sigmoid(10d-50)
            hs[lane][t] = h;
        }
        out[PP + (size_t)p] = dmin;
        float* hp = out + 2 * (size_t)PP + (size_t)p * 10;
#pragma unroll
        for (int t = 0; t < 10; ++t) hp[t] = hs[lane][t];
    }
    __syncthreads();

    float hist[10];
#pragma unroll
    for (int t = 0; t < 10; ++t) hist[t] = hs[lane][t];

    // ---- phase 1: L1 activations for o-window [32*wv, 32*wv+32) ----
    {
        const float* giRow = gi_t + (size_t)i * 256 + wv * 32;
        float4 giv[8];
#pragma unroll
        for (int q = 0; q < 8; ++q)
            giv[q] = *reinterpret_cast<const float4*>(giRow + q * 4);
        const float* gif = &giv[0].x;

        unsigned int ahp[16], alp[16];
#pragma unroll
        for (int q2 = 0; q2 < 8; ++q2) {
            const int o = (wv << 5) + 4 * q2;
            const float4 gj4 = *reinterpret_cast<const float4*>(
                gjT4 + ((size_t)(o >> 2) * NN + j) * 4);
            float av[4];
#pragma unroll
            for (int k = 0; k < 4; ++k) {
                float a = gif[4 * q2 + k] + (&gj4.x)[k];
                const float* wh = e_w1 + (o + k) * 138 + 128;   // uniform -> scalar
#pragma unroll
                for (int t = 0; t < 10; ++t) a = fmaf(hist[t], wh[t], a);
                av[k] = fmaxf(a, 0.f);
            }
            const unsigned int u0 = __float_as_uint(av[0]), u1 = __float_as_uint(av[1]);
            const unsigned int u2 = __float_as_uint(av[2]), u3 = __float_as_uint(av[3]);
            ahp[2 * q2]     = __builtin_amdgcn_perm(u1, u0, 0x07060302);
            ahp[2 * q2 + 1] = __builtin_amdgcn_perm(u3, u2, 0x07060302);
            const float l0 = av[0] - __uint_as_float(u0 & 0xFFFF0000u);
            const float l1 = av[1] - __uint_as_float(u1 & 0xFFFF0000u);
            const float l2 = av[2] - __uint_as_float(u2 & 0xFFFF0000u);
            const float l3 = av[3] - __uint_as_float(u3 & 0xFFFF0000u);
            alp[2 * q2]     = __builtin_amdgcn_perm(__float_as_uint(l1), __float_as_uint(l0), 0x07060302);
            alp[2 * q2 + 1] = __builtin_amdgcn_perm(__float_as_uint(l3), __float_as_uint(l2), 0x07060302);
        }

        char* ahb = (char*)Ah + lane * 256;
        char* alb = (char*)Al + lane * 256;
#pragma unroll
        for (int c = 0; c < 4; ++c) {
            const int boff = ((wv << 6) + (c << 4)) ^ ((lane & 7) << 4);
            *reinterpret_cast<uint4*>(ahb + boff) = *reinterpret_cast<uint4*>(&ahp[4 * c]);
            *reinterpret_cast<uint4*>(alb + boff) = *reinterpret_cast<uint4*>(&alp[4 * c]);
        }
    }

    // ---- B-frags for m-tile nt = wv ----
    bf16x8 bh[4], bl[4];
#pragma unroll
    for (int kk = 0; kk < 4; ++kk) {
        const unsigned short* bb = w2f + ((size_t)(wv * 4 + kk) * 2) * 512 + lane * 8;
        bh[kk] = *reinterpret_cast<const bf16x8*>(bb);
        bl[kk] = *reinterpret_cast<const bf16x8*>(bb + 512);
    }
    __syncthreads();

    // ---- phase 2: MFMA, K = 128, 3-term ----
    f32x4 acc[4];
#pragma unroll
    for (int pt = 0; pt < 4; ++pt) acc[pt] = (f32x4){0.f, 0.f, 0.f, 0.f};

    const char* ahr = (const char*)Ah;
    const char* alr = (const char*)Al;
#pragma unroll
    for (int kk = 0; kk < 4; ++kk) {
        const int boff = ((kk << 6) + ((lane >> 4) << 4)) ^ ((lane & 7) << 4);
#pragma unroll
        for (int pt = 0; pt < 4; ++pt) {
            const int row = pt * 16 + (lane & 15);
            bf16x8 afh = *reinterpret_cast<const bf16x8*>(ahr + row * 256 + boff);
            bf16x8 afl = *reinterpret_cast<const bf16x8*>(alr + row * 256 + boff);
            acc[pt] = __builtin_amdgcn_mfma_f32_16x16x32_bf16(afh, bh[kk], acc[pt], 0, 0, 0);
            acc[pt] = __builtin_amdgcn_mfma_f32_16x16x32_bf16(afh, bl[kk], acc[pt], 0, 0, 0);
            acc[pt] = __builtin_amdgcn_mfma_f32_16x16x32_bf16(afl, bh[kk], acc[pt], 0, 0, 0);
        }
    }

    // ---- epilogue ----
    {
        const int m = wv * 16 + (lane & 15);
        const float w3v = e_w3[m];
        const float b2v = e_b2[m];
#pragma unroll
        for (int pt = 0; pt < 4; ++pt) {
            float zs0 = fmaxf(acc[pt][0] + b2v, 0.f) * w3v;
            float zs1 = fmaxf(acc[pt][1] + b2v, 0.f) * w3v;
            float zs2 = fmaxf(acc[pt][2] + b2v, 0.f) * w3v;
            float zs3 = fmaxf(acc[pt][3] + b2v, 0.f) * w3v;
#pragma unroll
            for (int msk = 1; msk < 16; msk <<= 1) {
                zs0 += __shfl_xor(zs0, msk);
                zs1 += __shfl_xor(zs1, msk);
                zs2 += __shfl_xor(zs2, msk);
                zs3 += __shfl_xor(zs3, msk);
            }
            if ((lane & 15) == 0) {
                const int pr = pt * 16 + (lane >> 4) * 4;
                zsh[wv][pr]     = zs0;
                zsh[wv][pr + 1] = zs1;
                zsh[wv][pr + 2] = zs2;
                zsh[wv][pr + 3] = zs3;
            }
        }
    }
    __syncthreads();

    if (wv == 0) {
        float z = zsh[0][lane] + zsh[1][lane] + zsh[2][lane] + zsh[3][lane] + e_b3[0];
        out[p] = fsigmoid_neg(-z);
    }
}

extern "C" void kernel_launch(void* const* d_in, const int* in_sizes, int n_in,
                              void* d_out, int out_size, void* d_ws, size_t ws_size,
                              hipStream_t stream) {
    const float* traj   = (const float*)d_in[0];
    const float* adj    = (const float*)d_in[1];
    const float* w_in   = (const float*)d_in[2];
    const float* b_in   = (const float*)d_in[3];
    const float* w_out  = (const float*)d_in[4];
    const float* b_out  = (const float*)d_in[5];
    const float* ln1g   = (const float*)d_in[6];
    const float* ln1b   = (const float*)d_in[7];
    const float* fw1    = (const float*)d_in[8];
    const float* fb1    = (const float*)d_in[9];
    const float* fw2    = (const float*)d_in[10];
    const float* fb2    = (const float*)d_in[11];
    const float* ln2g   = (const float*)d_in[12];
    const float* ln2b   = (const float*)d_in[13];
    const float* gcn_w  = (const float*)d_in[14];
    const float* gcn_b  = (const float*)d_in[15];
    const float* e_w1   = (const float*)d_in[16];
    const float* e_b1   = (const float*)d_in[17];
    const float* e_w2   = (const float*)d_in[18];
    const float* e_b2   = (const float*)d_in[19];
    const float* e_w3   = (const float*)d_in[20];
    const float* e_b3   = (const float*)d_in[21];

    float* ws    = (float*)d_ws;
    unsigned short* w2f = (unsigned short*)(ws + WS_W2F);
    float* txyT  = ws + WS_TXYT;
    float* partb = ws + WS_PART;     // gi colocated post-red3 (stride 256/row)
    float* gjT4  = ws + WS_GJT4;
    float* g1b   = ws + WS_GJT4;     // time-shared: g1b dead before gjT4 written
    float* slotA = ws + WS_SLOTA;    // node0, later g2b

    // 1. transformer (+ aux w2f/txyT blocks)
    k_transformer<<<NN + 84, 128, 0, stream>>>(traj, w_in, b_in, w_out, b_out,
                                               ln1g, ln1b, fw1, fb1, fw2, fb2,
                                               ln2g, ln2b, e_w2,
                                               slotA, w2f, txyT);

    dim3 pgrid(NN / 8, JSPLIT);
    // layer 1: node0(slotA) -> g1b
    k_gcn_part<<<pgrid, 256, 0, stream>>>(adj, slotA, partb);
    k_gcn_red <<<NN / 4, 256, 0, stream>>>(partb, gcn_w, gcn_b, g1b);
    // layer 2: g1b -> g2b(slotA)
    k_gcn_part<<<pgrid, 256, 0, stream>>>(adj, g1b, partb);
    k_gcn_red <<<NN / 4, 256, 0, stream>>>(partb, gcn_w + 4096, gcn_b + 64, slotA);
    // layer 3: g2b(slotA) -> fused red3: gi (into partb rows) + gjT4
    k_gcn_part<<<pgrid, 256, 0, stream>>>(adj, slotA, partb);
    k_gcn_red3<<<NN / 4, 256, 0, stream>>>(partb, gcn_w + 8192, gcn_b + 128,
                                           e_w1, e_b1, gjT4);

    k_edge<<<PP / 64, 256, 0, stream>>>(txyT, partb, gjT4, e_w1, w2f, e_b2,
                                        e_w3, e_b3, (float*)d_out);
}

// Round 11
// 316.985 us; speedup vs baseline: 1.4151x; 1.0202x over previous
//
#include <hip/hip_runtime.h>
#include <hip/hip_bf16.h>
#include <math.h>

#define NN 1536
#define TT 10
#define DD 64
#define NHEAD 4
#define HDIM 16
#define PP 1178880   // NN*(NN-1)/2 = 4605 * 256 exactly; = 18420 * 64

// ws layout (float offsets)
#define WS_W2F   0        // 16384 ushort = 8192 float slots
#define WS_TXYT  8192     // 20*1536 = 30720 -> 38912
#define WS_GI    38912    // 1536*128 = 196608 -> 235520
#define WS_GJT4  235520   // 196608 -> 432128
#define WS_NODEA 432128   // 98304 -> 530432
#define WS_NODEB 530432   // 98304 -> 628736

using bf16x8 = __attribute__((ext_vector_type(8))) short;
using f32x4  = __attribute__((ext_vector_type(4))) float;

static __device__ __forceinline__ float fsqrt(float x) { return __builtin_amdgcn_sqrtf(x); }
static __device__ __forceinline__ float frcp(float x)  { return __builtin_amdgcn_rcpf(x); }
static __device__ __forceinline__ float fexp(float x)  {
    return __builtin_amdgcn_exp2f(x * 1.44269504088896f);
}
static __device__ __forceinline__ float fsigmoid_neg(float e_arg) {
    return frcp(1.f + fexp(e_arg));     // 1/(1+exp(e_arg))
}

static __device__ __forceinline__ unsigned short f2bf_rn(float f) {
    unsigned int u = __float_as_uint(f);
    unsigned int r = (u + 0x7FFFu + ((u >> 16) & 1u)) >> 16;
    return (unsigned short)r;
}
static __device__ __forceinline__ float bf2f(unsigned short h) {
    return __uint_as_float(((unsigned int)h) << 16);
}

static __device__ __forceinline__ float dot64(const float* __restrict__ a,
                                              const float* __restrict__ b) {
    float s = 0.f;
#pragma unroll
    for (int c = 0; c < 64; c += 4) {
        float4 av = *reinterpret_cast<const float4*>(a + c);
        float4 bv = *reinterpret_cast<const float4*>(b + c);
        s = fmaf(av.x, bv.x, s);
        s = fmaf(av.y, bv.y, s);
        s = fmaf(av.z, bv.z, s);
        s = fmaf(av.w, bv.w, s);
    }
    return s;
}

// accumulate 16-wide chunk: acc += x[0..15] . w(4 float4 regs)
#define FMA16(acc, xr, w0, w1, w2, w3)                                   \
    {                                                                    \
        float4 x0 = *reinterpret_cast<const float4*>(xr);                \
        float4 x1 = *reinterpret_cast<const float4*>(xr + 4);            \
        float4 x2 = *reinterpret_cast<const float4*>(xr + 8);            \
        float4 x3 = *reinterpret_cast<const float4*>(xr + 12);           \
        acc = fmaf(x0.x, w0.x, acc); acc = fmaf(x0.y, w0.y, acc);        \
        acc = fmaf(x0.z, w0.z, acc); acc = fmaf(x0.w, w0.w, acc);        \
        acc = fmaf(x1.x, w1.x, acc); acc = fmaf(x1.y, w1.y, acc);        \
        acc = fmaf(x1.z, w1.z, acc); acc = fmaf(x1.w, w1.w, acc);        \
        acc = fmaf(x2.x, w2.x, acc); acc = fmaf(x2.y, w2.y, acc);        \
        acc = fmaf(x2.z, w2.z, acc); acc = fmaf(x2.w, w2.w, acc);        \
        acc = fmaf(x3.x, w3.x, acc); acc = fmaf(x3.y, w3.y, acc);        \
        acc = fmaf(x3.z, w3.z, acc); acc = fmaf(x3.w, w3.w, acc);        \
    }

// ---------------- Transformer encoder layer (+aux: w2f, txyT), 128 thr/block ----------------
__global__ __launch_bounds__(128) void k_transformer(
    const float* __restrict__ traj,
    const float* __restrict__ wqkv, const float* __restrict__ bqkv,
    const float* __restrict__ wo,   const float* __restrict__ bo,
    const float* __restrict__ g1,   const float* __restrict__ b1,
    const float* __restrict__ fw1,  const float* __restrict__ fb1,
    const float* __restrict__ fw2,  const float* __restrict__ fb2,
    const float* __restrict__ g2,   const float* __restrict__ b2,
    const float* __restrict__ e_w2,
    float* __restrict__ node_out, unsigned short* __restrict__ w2f,
    float* __restrict__ txyT)
{
    const int bid = blockIdx.x, tid = threadIdx.x;

    if (bid >= NN) {
        const int s = bid - NN;
        if (s < 64) {
#pragma unroll
            for (int q = 0; q < 2; ++q) {
                const int idx = s * 256 + q * 128 + tid;
                int e = idx & 7, lane = (idx >> 3) & 63;
                int half = (idx >> 9) & 1, kk = (idx >> 10) & 3, nt = (idx >> 12) & 3;
                int n = nt * 16 + (lane & 15);
                int k = kk * 32 + (lane >> 4) * 8 + e;
                float v = e_w2[n * 128 + k];
                unsigned short hi = f2bf_rn(v);
                unsigned short lo = f2bf_rn(v - bf2f(hi));
                w2f[idx] = half ? lo : hi;
            }
        } else {
            const int tc = s - 64;       // 0..19
            const int t = tc >> 1, c = tc & 1;
            for (int j = tid; j < NN; j += 128)
                txyT[(size_t)tc * NN + j] = traj[((size_t)j * TT + t) * DD + c];
        }
        return;
    }

    __shared__ __align__(16) float xs[TT][DD];
    __shared__ __align__(16) float qkvs[TT][3 * DD];
    __shared__ __align__(16) float cs[TT][DD];
    __shared__ __align__(16) float ys[TT][DD];
    __shared__ float mv[TT][2];

    const float* xg = traj + (size_t)bid * TT * DD;
    for (int idx = tid; idx < TT * DD; idx += 128)
        xs[idx / DD][idx % DD] = xg[idx];
    __syncthreads();

    // ---- QKV ----
    {
        float acc[TT];
        const float bq = bqkv[tid];
#pragma unroll
        for (int t = 0; t < TT; ++t) acc[t] = bq;
        const float* wrow = wqkv + (size_t)tid * DD;
#pragma unroll
        for (int c = 0; c < 4; ++c) {
            float4 w0 = *reinterpret_cast<const float4*>(wrow + 16 * c);
            float4 w1 = *reinterpret_cast<const float4*>(wrow + 16 * c + 4);
            float4 w2 = *reinterpret_cast<const float4*>(wrow + 16 * c + 8);
            float4 w3 = *reinterpret_cast<const float4*>(wrow + 16 * c + 12);
#pragma unroll
            for (int t = 0; t < TT; ++t)
                FMA16(acc[t], &xs[t][16 * c], w0, w1, w2, w3);
        }
#pragma unroll
        for (int t = 0; t < TT; ++t) qkvs[t][tid] = acc[t];

        const int o2 = 128 + (tid >> 1);
        const int t0 = (tid & 1) * 5;
        float acc2[5];
        const float bq2 = bqkv[o2];
#pragma unroll
        for (int tt = 0; tt < 5; ++tt) acc2[tt] = bq2;
        const float* wrow2 = wqkv + (size_t)o2 * DD;
#pragma unroll
        for (int c = 0; c < 4; ++c) {
            float4 w0 = *reinterpret_cast<const float4*>(wrow2 + 16 * c);
            float4 w1 = *reinterpret_cast<const float4*>(wrow2 + 16 * c + 4);
            float4 w2 = *reinterpret_cast<const float4*>(wrow2 + 16 * c + 8);
            float4 w3 = *reinterpret_cast<const float4*>(wrow2 + 16 * c + 12);
#pragma unroll
            for (int tt = 0; tt < 5; ++tt)
                FMA16(acc2[tt], &xs[t0 + tt][16 * c], w0, w1, w2, w3);
        }
#pragma unroll
        for (int tt = 0; tt < 5; ++tt) qkvs[t0 + tt][o2] = acc2[tt];
    }
    __syncthreads();

    // ---- attention ----
    if (tid < NHEAD * TT) {
        int h = tid / TT, t = tid % TT;
        float sc[TT];
        float mx = -1e30f;
#pragma unroll
        for (int s = 0; s < TT; ++s) {
            float a = 0.f;
#pragma unroll
            for (int d = 0; d < HDIM; ++d)
                a = fmaf(qkvs[t][h * HDIM + d], qkvs[s][DD + h * HDIM + d], a);
            a *= 0.25f;
            sc[s] = a;
            mx = fmaxf(mx, a);
        }
        float den = 0.f;
#pragma unroll
        for (int s = 0; s < TT; ++s) { sc[s] = fexp(sc[s] - mx); den += sc[s]; }
        float inv = frcp(den);
#pragma unroll
        for (int d = 0; d < HDIM; ++d) {
            float a = 0.f;
#pragma unroll
            for (int s = 0; s < TT; ++s)
                a = fmaf(sc[s], qkvs[s][2 * DD + h * HDIM + d], a);
            cs[t][h * HDIM + d] = a * inv;
        }
    }
    __syncthreads();

    // ---- out-proj + residual ----
    {
        const int o = tid & 63, t0 = (tid >> 6) * 5;
        float acc[5];
        const float bv = bo[o];
#pragma unroll
        for (int tt = 0; tt < 5; ++tt) acc[tt] = bv;
        const float* wrow = wo + (size_t)o * DD;
#pragma unroll
        for (int c = 0; c < 4; ++c) {
            float4 w0 = *reinterpret_cast<const float4*>(wrow + 16 * c);
            float4 w1 = *reinterpret_cast<const float4*>(wrow + 16 * c + 4);
            float4 w2 = *reinterpret_cast<const float4*>(wrow + 16 * c + 8);
            float4 w3 = *reinterpret_cast<const float4*>(wrow + 16 * c + 12);
#pragma unroll
            for (int tt = 0; tt < 5; ++tt)
                FMA16(acc[tt], &cs[t0 + tt][16 * c], w0, w1, w2, w3);
        }
#pragma unroll
        for (int tt = 0; tt < 5; ++tt)
            ys[t0 + tt][o] = xs[t0 + tt][o] + acc[tt];
    }
    __syncthreads();

    // ---- LN1 stats ----
    {
        const int t8 = tid >> 3, s8 = tid & 7;
        if (t8 < TT) {
            const float* yr = &ys[t8][s8 * 8];
            float s1 = 0.f;
#pragma unroll
            for (int c = 0; c < 8; c += 4) {
                float4 v = *reinterpret_cast<const float4*>(yr + c);
                s1 += (v.x + v.y) + (v.z + v.w);
            }
#pragma unroll
            for (int m = 1; m < 8; m <<= 1) s1 += __shfl_xor(s1, m);
            const float mean = s1 * (1.f / DD);
            float s2 = 0.f;
#pragma unroll
            for (int c = 0; c < 8; c += 4) {
                float4 v = *reinterpret_cast<const float4*>(yr + c);
                float d0 = v.x - mean, d1 = v.y - mean, d2 = v.z - mean, d3 = v.w - mean;
                s2 = fmaf(d0, d0, fmaf(d1, d1, fmaf(d2, d2, fmaf(d3, d3, s2))));
            }
#pragma unroll
            for (int m = 1; m < 8; m <<= 1) s2 += __shfl_xor(s2, m);
            if (s8 == 0) {
                mv[t8][0] = mean;
                mv[t8][1] = rsqrtf(s2 * (1.f / DD) + 1e-5f);
            }
        }
    }
    __syncthreads();
    for (int idx = tid; idx < TT * DD; idx += 128) {
        int t = idx / DD, o = idx % DD;
        xs[t][o] = (ys[t][o] - mv[t][0]) * mv[t][1] * g1[o] + b1[o];
    }
    __syncthreads();

    // ---- FF1 ----
    {
        const int pcol = tid & 63, t0 = (tid >> 6) * 5;
        float acc[5];
        const float bv = fb1[pcol];
#pragma unroll
        for (int tt = 0; tt < 5; ++tt) acc[tt] = bv;
        const float* wrow = fw1 + (size_t)pcol * DD;
#pragma unroll
        for (int c = 0; c < 4; ++c) {
            float4 w0 = *reinterpret_cast<const float4*>(wrow + 16 * c);
            float4 w1 = *reinterpret_cast<const float4*>(wrow + 16 * c + 4);
            float4 w2 = *reinterpret_cast<const float4*>(wrow + 16 * c + 8);
            float4 w3 = *reinterpret_cast<const float4*>(wrow + 16 * c + 12);
#pragma unroll
            for (int tt = 0; tt < 5; ++tt)
                FMA16(acc[tt], &xs[t0 + tt][16 * c], w0, w1, w2, w3);
        }
#pragma unroll
        for (int tt = 0; tt < 5; ++tt)
            cs[t0 + tt][pcol] = fmaxf(acc[tt], 0.f);
    }
    __syncthreads();

    // ---- FF2 + residual ----
    {
        const int o = tid & 63, t0 = (tid >> 6) * 5;
        float acc[5];
        const float bv = fb2[o];
#pragma unroll
        for (int tt = 0; tt < 5; ++tt) acc[tt] = bv;
        const float* wrow = fw2 + (size_t)o * DD;
#pragma unroll
        for (int c = 0; c < 4; ++c) {
            float4 w0 = *reinterpret_cast<const float4*>(wrow + 16 * c);
            float4 w1 = *reinterpret_cast<const float4*>(wrow + 16 * c + 4);
            float4 w2 = *reinterpret_cast<const float4*>(wrow + 16 * c + 8);
            float4 w3 = *reinterpret_cast<const float4*>(wrow + 16 * c + 12);
#pragma unroll
            for (int tt = 0; tt < 5; ++tt)
                FMA16(acc[tt], &cs[t0 + tt][16 * c], w0, w1, w2, w3);
        }
#pragma unroll
        for (int tt = 0; tt < 5; ++tt)
            ys[t0 + tt][o] = xs[t0 + tt][o] + acc[tt];
    }
    __syncthreads();

    // ---- LN2 stats ----
    {
        const int t8 = tid >> 3, s8 = tid & 7;
        if (t8 < TT) {
            const float* yr = &ys[t8][s8 * 8];
            float s1 = 0.f;
#pragma unroll
            for (int c = 0; c < 8; c += 4) {
                float4 v = *reinterpret_cast<const float4*>(yr + c);
                s1 += (v.x + v.y) + (v.z + v.w);
            }
#pragma unroll
            for (int m = 1; m < 8; m <<= 1) s1 += __shfl_xor(s1, m);
            const float mean = s1 * (1.f / DD);
            float s2 = 0.f;
#pragma unroll
            for (int c = 0; c < 8; c += 4) {
                float4 v = *reinterpret_cast<const float4*>(yr + c);
                float d0 = v.x - mean, d1 = v.y - mean, d2 = v.z - mean, d3 = v.w - mean;
                s2 = fmaf(d0, d0, fmaf(d1, d1, fmaf(d2, d2, fmaf(d3, d3, s2))));
            }
#pragma unroll
            for (int m = 1; m < 8; m <<= 1) s2 += __shfl_xor(s2, m);
            if (s8 == 0) {
                mv[t8][0] = mean;
                mv[t8][1] = rsqrtf(s2 * (1.f / DD) + 1e-5f);
            }
        }
    }
    __syncthreads();

    if (tid < DD) {
        float acc = 0.f;
#pragma unroll
        for (int t = 0; t < TT; ++t)
            acc += (ys[t][tid] - mv[t][0]) * mv[t][1];
        node_out[bid * DD + tid] = acc * g2[tid] * (1.f / TT) + b2[tid];
    }
}

// ---------------- GCN fused layer: Y = relu((A@X)@W^T + b); 512 thr, 4 rows/blk ----------------
__global__ __launch_bounds__(512) void k_gcn(
    const float* __restrict__ A, const float* __restrict__ X,
    const float* __restrict__ W, const float* __restrict__ b,
    float* __restrict__ Y)
{
    __shared__ __align__(16) float part[8][68];
    const int tid = threadIdx.x;
    const int lane = tid & 63;
    const int wv = tid >> 6;               // 0..7: row r = wv>>1, j-half = wv&1
    const int r = wv >> 1, jh = wv & 1;
    const int i = __builtin_amdgcn_readfirstlane(blockIdx.x * 4 + r);

    const float* arow = A + (size_t)i * NN + jh * (NN / 2);
    const float* xp = X + (size_t)jh * (NN / 2) * 64 + lane;
    float acc = 0.f;
#pragma unroll 8
    for (int jj = 0; jj < NN / 2; ++jj)
        acc = fmaf(arow[jj], xp[(size_t)jj * 64], acc);
    part[wv][lane] = acc;
    __syncthreads();

    if (tid < 256) {
        const int o = tid & 63, r2 = tid >> 6;
        float z = b[o] + dot64(&part[2 * r2][0], W + o * 64)
                       + dot64(&part[2 * r2 + 1][0], W + o * 64);
        Y[(size_t)(blockIdx.x * 4 + r2) * 64 + o] = fmaxf(z, 0.f);
    }
}

// ---------------- GCN layer 3 + fused edge-prep (gi, gjT4) ----------------
__global__ __launch_bounds__(512) void k_gcn3(
    const float* __restrict__ A, const float* __restrict__ X,
    const float* __restrict__ W, const float* __restrict__ b,
    const float* __restrict__ e_w1, const float* __restrict__ e_b1,
    float* __restrict__ gi_t, float* __restrict__ gjT4)
{
    __shared__ __align__(16) float part[8][68];
    __shared__ __align__(16) float nrow[4][68];
    const int tid = threadIdx.x;
    const int lane = tid & 63;
    const int wv = tid >> 6;
    const int r = wv >> 1, jh = wv & 1;
    const int i = __builtin_amdgcn_readfirstlane(blockIdx.x * 4 + r);

    const float* arow = A + (size_t)i * NN + jh * (NN / 2);
    const float* xp = X + (size_t)jh * (NN / 2) * 64 + lane;
    float acc = 0.f;
#pragma unroll 8
    for (int jj = 0; jj < NN / 2; ++jj)
        acc = fmaf(arow[jj], xp[(size_t)jj * 64], acc);
    part[wv][lane] = acc;
    __syncthreads();

    if (tid < 256) {
        const int o = tid & 63, r2 = tid >> 6;
        float z = b[o] + dot64(&part[2 * r2][0], W + o * 64)
                       + dot64(&part[2 * r2 + 1][0], W + o * 64);
        nrow[r2][o] = fmaxf(z, 0.f);
    }
    __syncthreads();

    // gi + gjT4: 512 threads = 4 rows x 128 o, one of each per thread
    const int rr = tid >> 7;        // 0..3
    const int oo = tid & 127;
    const int i2 = blockIdx.x * 4 + rr;
    gi_t[(size_t)i2 * 128 + oo] = e_b1[oo] + dot64(&nrow[rr][0], e_w1 + oo * 138);
    gjT4[((size_t)(oo >> 2) * NN + i2) * 4 + (oo & 3)] =
        dot64(&nrow[rr][0], e_w1 + oo * 138 + 64);
}

// ---------------- edge predictor: MFMA, 64 pairs/block, 4 waves, half-K tiles ----------------
__global__ __launch_bounds__(256, 7) void k_edge(
    const float* __restrict__ txyT,
    const float* __restrict__ gi_t, const float* __restrict__ gjT4,
    const float* __restrict__ e_w1,
    const unsigned short* __restrict__ w2f, const float* __restrict__ e_b2,
    const float* __restrict__ e_w3, const float* __restrict__ e_b3,
    float* __restrict__ out)
{
    __shared__ __align__(16) unsigned short Ah[64 * 64];
    __shared__ __align__(16) unsigned short Al[64 * 64];
    __shared__ float hs[64][11];
    __shared__ float zsh[4][64];

    const int tid  = threadIdx.x;
    const int lane = tid & 63;
    const int wv   = __builtin_amdgcn_readfirstlane(tid >> 6);  // wave 0..3
    const int p    = blockIdx.x * 64 + lane;

    // invert p -> (pi, pj)
    const float Df = (float)((2 * NN - 1) * (2 * NN - 1) - 8 * p);
    int pi = (int)(((float)(2 * NN - 1) - fsqrt(Df)) * 0.5f);
    pi = pi < 0 ? 0 : (pi > NN - 2 ? NN - 2 : pi);
    while (pi * (2 * NN - 1 - pi) / 2 > p) --pi;
    while ((pi + 1) * (2 * NN - 2 - pi) / 2 <= p) ++pi;
    const int pj = pi + 1 + (p - pi * (2 * NN - 1 - pi) / 2);

    // ---- hist + dmin: wave 0 -> LDS + out ----
    if (wv == 0) {
        float dmin = 3.4e38f;
#pragma unroll
        for (int t = 0; t < 10; ++t) {
            float dx = txyT[(size_t)(2 * t) * NN + pi] - txyT[(size_t)(2 * t) * NN + pj];
            float dy = txyT[(size_t)(2 * t + 1) * NN + pi] - txyT[(size_t)(2 * t + 1) * NN + pj];
            float d = fsqrt(fmaf(dx, dx, dy * dy));
            dmin = fminf(dmin, d);
            float h = fsigmoid_neg(50.f - 10.f * d);   // sigmoid(10d-50)
            hs[lane][t] = h;
        }
        out[PP + (size_t)p] = dmin;
        float* hp = out + 2 * (size_t)PP + (size_t)p * 10;
#pragma unroll
        for (int t = 0; t < 10; ++t) hp[t] = hs[lane][t];
    }
    __syncthreads();

    float hist[10];
#pragma unroll
    for (int t = 0; t < 10; ++t) hist[t] = hs[lane][t];

    f32x4 acc[4];
#pragma unroll
    for (int pt = 0; pt < 4; ++pt) acc[pt] = (f32x4){0.f, 0.f, 0.f, 0.f};

#pragma unroll
    for (int h = 0; h < 2; ++h) {
        // ---- phase 1: 16 o's for o-window [h*64 + wv*16, +16) ----
        const int ob = h * 64 + wv * 16;
        const float* giRow = gi_t + (size_t)pi * 128 + ob;
        unsigned int ahp[8], alp[8];
#pragma unroll
        for (int q2 = 0; q2 < 4; ++q2) {
            const int o = ob + 4 * q2;
            const float4 gi4 = *reinterpret_cast<const float4*>(giRow + 4 * q2);
            const float4 gj4 = *reinterpret_cast<const float4*>(
                gjT4 + ((size_t)(o >> 2) * NN + pj) * 4);
            float av[4];
#pragma unroll
            for (int k = 0; k < 4; ++k) {
                float a = (&gi4.x)[k] + (&gj4.x)[k];
                const float* wh = e_w1 + (o + k) * 138 + 128;   // uniform -> scalar
#pragma unroll
                for (int t = 0; t < 10; ++t) a = fmaf(hist[t], wh[t], a);
                av[k] = fmaxf(a, 0.f);
            }
            const unsigned int u0 = __float_as_uint(av[0]), u1 = __float_as_uint(av[1]);
            const unsigned int u2 = __float_as_uint(av[2]), u3 = __float_as_uint(av[3]);
            ahp[2 * q2]     = __builtin_amdgcn_perm(u1, u0, 0x07060302);
            ahp[2 * q2 + 1] = __builtin_amdgcn_perm(u3, u2, 0x07060302);
            const float l0 = av[0] - __uint_as_float(u0 & 0xFFFF0000u);
            const float l1 = av[1] - __uint_as_float(u1 & 0xFFFF0000u);
            const float l2 = av[2] - __uint_as_float(u2 & 0xFFFF0000u);
            const float l3 = av[3] - __uint_as_float(u3 & 0xFFFF0000u);
            alp[2 * q2]     = __builtin_amdgcn_perm(__float_as_uint(l1), __float_as_uint(l0), 0x07060302);
            alp[2 * q2 + 1] = __builtin_amdgcn_perm(__float_as_uint(l3), __float_as_uint(l2), 0x07060302);
        }

        if (h == 1) __syncthreads();    // all waves done reading half-0 tiles

        // write tiles: row = lane (128 B rows), slot = wv*2 + c, XOR row swizzle
        char* ahb = (char*)Ah + lane * 128;
        char* alb = (char*)Al + lane * 128;
#pragma unroll
        for (int c = 0; c < 2; ++c) {
            const int boff = ((wv << 5) + (c << 4)) ^ ((lane & 7) << 4);
            *reinterpret_cast<uint4*>(ahb + boff) = *reinterpret_cast<uint4*>(&ahp[4 * c]);
            *reinterpret_cast<uint4*>(alb + boff) = *reinterpret_cast<uint4*>(&alp[4 * c]);
        }

        // B-frags for this half: global kk = 2h + kkl
        bf16x8 bh[2], bl[2];
#pragma unroll
        for (int kkl = 0; kkl < 2; ++kkl) {
            const unsigned short* bb =
                w2f + ((size_t)(wv * 4 + 2 * h + kkl) * 2) * 512 + lane * 8;
            bh[kkl] = *reinterpret_cast<const bf16x8*>(bb);
            bl[kkl] = *reinterpret_cast<const bf16x8*>(bb + 512);
        }
        __syncthreads();

        // ---- MFMA: 2 kkl x 4 pt x 3 terms ----
        const char* ahr = (const char*)Ah;
        const char* alr = (const char*)Al;
#pragma unroll
        for (int kkl = 0; kkl < 2; ++kkl) {
#pragma unroll
            for (int pt = 0; pt < 4; ++pt) {
                const int row = pt * 16 + (lane & 15);
                const int boff = ((kkl << 6) + ((lane >> 4) << 4)) ^ ((row & 7) << 4);
                bf16x8 afh = *reinterpret_cast<const bf16x8*>(ahr + row * 128 + boff);
                bf16x8 afl = *reinterpret_cast<const bf16x8*>(alr + row * 128 + boff);
                acc[pt] = __builtin_amdgcn_mfma_f32_16x16x32_bf16(afh, bh[kkl], acc[pt], 0, 0, 0);
                acc[pt] = __builtin_amdgcn_mfma_f32_16x16x32_bf16(afh, bl[kkl], acc[pt], 0, 0, 0);
                acc[pt] = __builtin_amdgcn_mfma_f32_16x16x32_bf16(afl, bh[kkl], acc[pt], 0, 0, 0);
            }
        }
    }

    // ---- epilogue ----
    {
        const int m = wv * 16 + (lane & 15);
        const float w3v = e_w3[m];
        const float b2v = e_b2[m];
#pragma unroll
        for (int pt = 0; pt < 4; ++pt) {
            float zs0 = fmaxf(acc[pt][0] + b2v, 0.f) * w3v;
            float zs1 = fmaxf(acc[pt][1] + b2v, 0.f) * w3v;
            float zs2 = fmaxf(acc[pt][2] + b2v, 0.f) * w3v;
            float zs3 = fmaxf(acc[pt][3] + b2v, 0.f) * w3v;
#pragma unroll
            for (int msk = 1; msk < 16; msk <<= 1) {
                zs0 += __shfl_xor(zs0, msk);
                zs1 += __shfl_xor(zs1, msk);
                zs2 += __shfl_xor(zs2, msk);
                zs3 += __shfl_xor(zs3, msk);
            }
            if ((lane & 15) == 0) {
                const int pr = pt * 16 + (lane >> 4) * 4;
                zsh[wv][pr]     = zs0;
                zsh[wv][pr + 1] = zs1;
                zsh[wv][pr + 2] = zs2;
                zsh[wv][pr + 3] = zs3;
            }
        }
    }
    __syncthreads();

    if (wv == 0) {
        float z = zsh[0][lane] + zsh[1][lane] + zsh[2][lane] + zsh[3][lane] + e_b3[0];
        out[p] = fsigmoid_neg(-z);
    }
}

extern "C" void kernel_launch(void* const* d_in, const int* in_sizes, int n_in,
                              void* d_out, int out_size, void* d_ws, size_t ws_size,
                              hipStream_t stream) {
    const float* traj   = (const float*)d_in[0];
    const float* adj    = (const float*)d_in[1];
    const float* w_in   = (const float*)d_in[2];
    const float* b_in   = (const float*)d_in[3];
    const float* w_out  = (const float*)d_in[4];
    const float* b_out  = (const float*)d_in[5];
    const float* ln1g   = (const float*)d_in[6];
    const float* ln1b   = (const float*)d_in[7];
    const float* fw1    = (const float*)d_in[8];
    const float* fb1    = (const float*)d_in[9];
    const float* fw2    = (const float*)d_in[10];
    const float* fb2    = (const float*)d_in[11];
    const float* ln2g   = (const float*)d_in[12];
    const float* ln2b   = (const float*)d_in[13];
    const float* gcn_w  = (const float*)d_in[14];
    const float* gcn_b  = (const float*)d_in[15];
    const float* e_w1   = (const float*)d_in[16];
    const float* e_b1   = (const float*)d_in[17];
    const float* e_w2   = (const float*)d_in[18];
    const float* e_b2   = (const float*)d_in[19];
    const float* e_w3   = (const float*)d_in[20];
    const float* e_b3   = (const float*)d_in[21];

    float* ws    = (float*)d_ws;
    unsigned short* w2f = (unsigned short*)(ws + WS_W2F);
    float* txyT  = ws + WS_TXYT;
    float* gi    = ws + WS_GI;
    float* gjT4  = ws + WS_GJT4;
    float* nodeA = ws + WS_NODEA;
    float* nodeB = ws + WS_NODEB;

    k_transformer<<<NN + 84, 128, 0, stream>>>(traj, w_in, b_in, w_out, b_out,
                                               ln1g, ln1b, fw1, fb1, fw2, fb2,
                                               ln2g, ln2b, e_w2,
                                               nodeA, w2f, txyT);

    k_gcn <<<NN / 4, 512, 0, stream>>>(adj, nodeA, gcn_w,        gcn_b,       nodeB);
    k_gcn <<<NN / 4, 512, 0, stream>>>(adj, nodeB, gcn_w + 4096, gcn_b + 64,  nodeA);
    k_gcn3<<<NN / 4, 512, 0, stream>>>(adj, nodeA, gcn_w + 8192, gcn_b + 128,
                                       e_w1, e_b1, gi, gjT4);

    k_edge<<<PP / 64, 256, 0, stream>>>(txyT, gi, gjT4, e_w1, w2f, e_b2,
                                        e_w3, e_b3, (float*)d_out);
}